// Round 1
// baseline (920.251 us; speedup 1.0000x reference)
//
#include <hip/hip_runtime.h>

#define NROWS 32768
#define DIM   512
#define KC    1024

// ---------------- e_norm2: ||E[k]||^2 ----------------
__global__ __launch_bounds__(256) void k_enorm(const float* __restrict__ E,
                                               float* __restrict__ en2) {
    int w = threadIdx.x >> 6, lane = threadIdx.x & 63;
    int c = blockIdx.x * 4 + w;
    const float* row = E + (size_t)c * DIM;
    float4 a = *reinterpret_cast<const float4*>(&row[lane * 8]);
    float4 b = *reinterpret_cast<const float4*>(&row[lane * 8 + 4]);
    float s = a.x*a.x + a.y*a.y + a.z*a.z + a.w*a.w
            + b.x*b.x + b.y*b.y + b.z*b.z + b.w*b.w;
    #pragma unroll
    for (int off = 32; off; off >>= 1) s += __shfl_xor(s, off);
    if (!lane) en2[c] = s;
}

// ---------------- argmin over codes (fused distance GEMM) ----------------
// block: 256 threads, 64 rows x 128-code tile, BD=32 LDS staging.
// thread tile: 4 rows x 8 codes (codes tc*4..+3 and 64+tc*4..+3).
__global__ __launch_bounds__(256) void k_argmin(const float* __restrict__ x,
                                                const float* __restrict__ E,
                                                const float* __restrict__ en2,
                                                int* __restrict__ idx) {
    __shared__ float xT[32][64];    // [d][row]   8 KB
    __shared__ float eT[32][128];   // [d][code] 16 KB
    const int tid = threadIdx.x;
    const int tr = tid >> 4;        // 0..15 (4 rows each)
    const int tc = tid & 15;        // 0..15 (8 codes each, split halves)
    const int row0 = blockIdx.x * 64;

    float best[4];
    int   bi[4];
    #pragma unroll
    for (int i = 0; i < 4; ++i) { best[i] = 3.4e38f; bi[i] = 0; }

    for (int ct = 0; ct < KC / 128; ++ct) {
        const int c0 = ct * 128;
        float acc[4][8];
        #pragma unroll
        for (int i = 0; i < 4; ++i)
            #pragma unroll
            for (int j = 0; j < 8; ++j) acc[i][j] = 0.f;

        for (int dt = 0; dt < DIM; dt += 32) {
            __syncthreads();
            // stage x tile: 64 rows x 32 d (transposed into LDS)
            #pragma unroll
            for (int h = 0; h < 2; ++h) {
                int f = tid + h * 256;            // 0..511 float4 slots
                int r = f >> 3, fd = (f & 7) * 4;
                float4 v = *reinterpret_cast<const float4*>(
                    &x[(size_t)(row0 + r) * DIM + dt + fd]);
                xT[fd + 0][r] = v.x; xT[fd + 1][r] = v.y;
                xT[fd + 2][r] = v.z; xT[fd + 3][r] = v.w;
            }
            // stage e tile: 128 codes x 32 d (transposed)
            #pragma unroll
            for (int h = 0; h < 4; ++h) {
                int f = tid + h * 256;            // 0..1023
                int c = f >> 3, fd = (f & 7) * 4;
                float4 v = *reinterpret_cast<const float4*>(
                    &E[(size_t)(c0 + c) * DIM + dt + fd]);
                eT[fd + 0][c] = v.x; eT[fd + 1][c] = v.y;
                eT[fd + 2][c] = v.z; eT[fd + 3][c] = v.w;
            }
            __syncthreads();
            #pragma unroll
            for (int d = 0; d < 32; ++d) {
                float4 xa = *reinterpret_cast<const float4*>(&xT[d][tr * 4]);
                float4 e0 = *reinterpret_cast<const float4*>(&eT[d][tc * 4]);
                float4 e1 = *reinterpret_cast<const float4*>(&eT[d][64 + tc * 4]);
                float xv[4] = {xa.x, xa.y, xa.z, xa.w};
                float ev[8] = {e0.x, e0.y, e0.z, e0.w, e1.x, e1.y, e1.z, e1.w};
                #pragma unroll
                for (int i = 0; i < 4; ++i)
                    #pragma unroll
                    for (int j = 0; j < 8; ++j)
                        acc[i][j] = fmaf(xv[i], ev[j], acc[i][j]);
            }
        }
        // epilogue for this code tile: dist = ||e||^2 - 2 x.e  (x^2 dropped)
        #pragma unroll
        for (int j = 0; j < 8; ++j) {
            int c = c0 + ((j < 4) ? (tc * 4 + j) : (64 + tc * 4 + (j - 4)));
            float e2 = en2[c];
            #pragma unroll
            for (int i = 0; i < 4; ++i) {
                float dist = e2 - 2.f * acc[i][j];
                if (dist < best[i] || (dist == best[i] && c < bi[i])) {
                    best[i] = dist; bi[i] = c;
                }
            }
        }
    }
    // reduce across the 16 threads (same tr) holding disjoint code subsets
    #pragma unroll
    for (int off = 1; off < 16; off <<= 1) {
        #pragma unroll
        for (int i = 0; i < 4; ++i) {
            float ob = __shfl_xor(best[i], off);
            int   oi = __shfl_xor(bi[i], off);
            if (ob < best[i] || (ob == best[i] && oi < bi[i])) {
                best[i] = ob; bi[i] = oi;
            }
        }
    }
    if (tc == 0) {
        #pragma unroll
        for (int i = 0; i < 4; ++i) idx[row0 + tr * 4 + i] = bi[i];
    }
}

// ---------------- histogram of idx ----------------
__global__ __launch_bounds__(256) void k_hist(const int* __restrict__ idx,
                                              int* __restrict__ counts) {
    __shared__ int h[KC];
    for (int i = threadIdx.x; i < KC; i += 256) h[i] = 0;
    __syncthreads();
    int g = blockIdx.x * 256 + threadIdx.x;
    atomicAdd(&h[idx[g]], 1);
    __syncthreads();
    for (int i = threadIdx.x; i < KC; i += 256)
        if (h[i]) atomicAdd(&counts[i], h[i]);
}

// ---------------- smoothing, perplexity, prefix sums ----------------
__global__ __launch_bounds__(1024) void k_meta(const int* __restrict__ counts,
                                               const float* __restrict__ ema_cs,
                                               float* __restrict__ smoothed,
                                               int* __restrict__ offsets,
                                               int* __restrict__ cursor,
                                               float* __restrict__ perp_out) {
    __shared__ float red[KC];
    __shared__ int sc[KC];
    int t = threadIdx.x;
    int cnt = counts[t];
    float cs = ema_cs[t] * 0.99f + 0.01f * (float)cnt;
    red[t] = cs; __syncthreads();
    for (int s = 512; s; s >>= 1) { if (t < s) red[t] += red[t + s]; __syncthreads(); }
    float n = red[0];
    __syncthreads();
    float sm = (cs + 1e-5f) / (n + 1024.f * 1e-5f) * n;
    smoothed[t] = sm;
    float p = (float)cnt / 32768.f;
    red[t] = p * logf(p + 1e-10f);
    __syncthreads();
    for (int s = 512; s; s >>= 1) { if (t < s) red[t] += red[t + s]; __syncthreads(); }
    if (!t) perp_out[0] = expf(-red[0]);
    // exclusive prefix sum of counts
    sc[t] = cnt; __syncthreads();
    for (int s = 1; s < KC; s <<= 1) {
        int v = (t >= s) ? sc[t - s] : 0;
        __syncthreads();
        sc[t] += v;
        __syncthreads();
    }
    int off = sc[t] - cnt;
    offsets[t] = off;
    cursor[t] = off;
}

// ---------------- CSR bucket scatter ----------------
__global__ __launch_bounds__(256) void k_scatter(const int* __restrict__ idx,
                                                 int* __restrict__ cursor,
                                                 int* __restrict__ bucket) {
    int g = blockIdx.x * 256 + threadIdx.x;
    int c = idx[g];
    int pos = atomicAdd(&cursor[c], 1);
    bucket[pos] = g;
}

// ---------------- segment-sum + new embedding ----------------
__global__ __launch_bounds__(256) void k_dw(const float* __restrict__ x,
                                            const float* __restrict__ ema_w,
                                            const int* __restrict__ offsets,
                                            const int* __restrict__ counts,
                                            const int* __restrict__ bucket,
                                            const float* __restrict__ smoothed,
                                            float* __restrict__ newE) {
    int k = blockIdx.x, t = threadIdx.x;
    int beg = offsets[k], m = counts[k];
    float a0 = 0.f, a1 = 0.f;
    for (int i = 0; i < m; ++i) {
        int r = bucket[beg + i];
        a0 += x[(size_t)r * DIM + t];
        a1 += x[(size_t)r * DIM + t + 256];
    }
    float sm = smoothed[k];
    newE[(size_t)k * DIM + t]       = (ema_w[(size_t)k * DIM + t]       * 0.99f + 0.01f * a0) / sm;
    newE[(size_t)k * DIM + t + 256] = (ema_w[(size_t)k * DIM + t + 256] * 0.99f + 0.01f * a1) / sm;
}

// ---------------- quantized output (STE) + loss partials ----------------
__global__ __launch_bounds__(256) void k_quant(const float* __restrict__ x,
                                               const int* __restrict__ idx,
                                               const float* __restrict__ newE,
                                               float* __restrict__ outq,
                                               float* __restrict__ partials) {
    int t0 = blockIdx.x * 256 + threadIdx.x;   // 4096*256 = 1048576 threads
    float lp = 0.f;
    #pragma unroll 4
    for (int s = 0; s < 16; ++s) {
        int e = t0 + s * 1048576;
        int row = e >> 9;
        int c = idx[row];
        float in = x[e];
        float q = newE[(size_t)c * DIM + (e & 511)];
        float d = q - in;
        outq[e] = in + d;
        lp += d * d;
    }
    #pragma unroll
    for (int off = 32; off; off >>= 1) lp += __shfl_xor(lp, off);
    __shared__ float wr[4];
    int lane = threadIdx.x & 63, w = threadIdx.x >> 6;
    if (!lane) wr[w] = lp;
    __syncthreads();
    if (threadIdx.x == 0) partials[blockIdx.x] = wr[0] + wr[1] + wr[2] + wr[3];
}

__global__ __launch_bounds__(256) void k_lossfin(const float* __restrict__ partials,
                                                 float* __restrict__ out0) {
    __shared__ double red[256];
    double s = 0.0;
    for (int i = threadIdx.x; i < 4096; i += 256) s += (double)partials[i];
    red[threadIdx.x] = s; __syncthreads();
    for (int st = 128; st; st >>= 1) {
        if (threadIdx.x < st) red[threadIdx.x] += red[threadIdx.x + st];
        __syncthreads();
    }
    if (!threadIdx.x) out0[0] = (float)(0.25 * red[0] / 16777216.0);
}

// ---------------- one-hot encodings scatter ----------------
__global__ __launch_bounds__(256) void k_onehot(const int* __restrict__ idx,
                                                float* __restrict__ enc) {
    int g = blockIdx.x * 256 + threadIdx.x;
    enc[(size_t)g * KC + idx[g]] = 1.0f;
}

extern "C" void kernel_launch(void* const* d_in, const int* in_sizes, int n_in,
                              void* d_out, int out_size, void* d_ws, size_t ws_size,
                              hipStream_t stream) {
    const float* x   = (const float*)d_in[0];   // inputs [32,1024,512]
    const float* E   = (const float*)d_in[1];   // embedding_weight [1024,512]
    const float* ecs = (const float*)d_in[2];   // ema_cluster_size [1024]
    const float* emw = (const float*)d_in[3];   // ema_w [1024,512]
    float* out = (float*)d_out;

    char* ws = (char*)d_ws;
    int*   idx      = (int*)(ws + 0);                 // 128 KB
    int*   bucket   = (int*)(ws + 131072);            // 128 KB
    float* en2      = (float*)(ws + 262144);          // 4 KB
    int*   counts   = (int*)(ws + 266240);            // 4 KB
    int*   offsets  = (int*)(ws + 270336);            // 4 KB
    int*   cursor   = (int*)(ws + 274432);            // 4 KB
    float* smoothed = (float*)(ws + 278528);          // 4 KB
    float* newE     = (float*)(ws + 282624);          // 2 MB
    float* partials = (float*)(ws + 282624 + 2097152); // 16 KB

    float* out_loss = out;                  // [1]
    float* out_q    = out + 1;              // [16777216]
    float* out_perp = out + 16777217;       // [1]
    float* out_enc  = out + 16777218;       // [33554432]

    hipMemsetAsync(counts, 0, KC * sizeof(int), stream);
    hipMemsetAsync(out_enc, 0, (size_t)NROWS * KC * sizeof(float), stream);

    k_enorm  <<<KC / 4, 256, 0, stream>>>(E, en2);
    k_argmin <<<NROWS / 64, 256, 0, stream>>>(x, E, en2, idx);
    k_hist   <<<NROWS / 256, 256, 0, stream>>>(idx, counts);
    k_meta   <<<1, 1024, 0, stream>>>(counts, ecs, smoothed, offsets, cursor, out_perp);
    k_scatter<<<NROWS / 256, 256, 0, stream>>>(idx, cursor, bucket);
    k_dw     <<<KC, 256, 0, stream>>>(x, emw, offsets, counts, bucket, smoothed, newE);
    k_quant  <<<4096, 256, 0, stream>>>(x, idx, newE, out_q, partials);
    k_lossfin<<<1, 256, 0, stream>>>(partials, out_loss);
    k_onehot <<<NROWS / 256, 256, 0, stream>>>(idx, out_enc);
}

// Round 2
// 798.015 us; speedup vs baseline: 1.1532x; 1.1532x over previous
//
#include <hip/hip_runtime.h>

#define NROWS 32768
#define DIM   512
#define KC    1024

// ---------------- e_norm2: ||E[k]||^2 ----------------
__global__ __launch_bounds__(256) void k_enorm(const float* __restrict__ E,
                                               float* __restrict__ en2) {
    int w = threadIdx.x >> 6, lane = threadIdx.x & 63;
    int c = blockIdx.x * 4 + w;
    const float* row = E + (size_t)c * DIM;
    float4 a = *reinterpret_cast<const float4*>(&row[lane * 8]);
    float4 b = *reinterpret_cast<const float4*>(&row[lane * 8 + 4]);
    float s = a.x*a.x + a.y*a.y + a.z*a.z + a.w*a.w
            + b.x*b.x + b.y*b.y + b.z*b.z + b.w*b.w;
    #pragma unroll
    for (int off = 32; off; off >>= 1) s += __shfl_xor(s, off);
    if (!lane) en2[c] = s;
}

// ---------------- argmin over codes (fused distance GEMM) ----------------
// block: 256 threads, 128 rows x 128 codes, 8x8 per-thread tile, BD=16.
// grid: (rowtile, codesplit) = (256, 8) -> 2048 blocks.
// LDS stride 132 (=4 mod 32): staging writes 2-way (free), reads conflict-free.
// cross-block argmin via packed (monotone_dist<<32 | code) atomicMin.
__global__ __launch_bounds__(256, 4) void k_argmin(const float* __restrict__ x,
                                                   const float* __restrict__ E,
                                                   const float* __restrict__ en2,
                                                   unsigned long long* __restrict__ packed) {
    __shared__ __align__(16) float xT[16][132];
    __shared__ __align__(16) float eT[16][132];
    const int tid = threadIdx.x;
    const int tr = tid >> 4;            // 0..15 -> rows tr*8..+7
    const int tc = tid & 15;            // 0..15 -> codes tc*4, 64+tc*4
    const int row0 = (blockIdx.x >> 3) * 128;
    const int c0   = (blockIdx.x & 7) * 128;

    float acc[8][8];
    #pragma unroll
    for (int i = 0; i < 8; ++i)
        #pragma unroll
        for (int j = 0; j < 8; ++j) acc[i][j] = 0.f;

    for (int dt = 0; dt < DIM; dt += 16) {
        __syncthreads();
        #pragma unroll
        for (int h = 0; h < 2; ++h) {
            int s = tid + h * 256;          // 0..511
            int r = s >> 2, fd = (s & 3) * 4;
            float4 v = *reinterpret_cast<const float4*>(
                &x[(size_t)(row0 + r) * DIM + dt + fd]);
            xT[fd + 0][r] = v.x; xT[fd + 1][r] = v.y;
            xT[fd + 2][r] = v.z; xT[fd + 3][r] = v.w;
            float4 w = *reinterpret_cast<const float4*>(
                &E[(size_t)(c0 + r) * DIM + dt + fd]);
            eT[fd + 0][r] = w.x; eT[fd + 1][r] = w.y;
            eT[fd + 2][r] = w.z; eT[fd + 3][r] = w.w;
        }
        __syncthreads();
        #pragma unroll
        for (int d = 0; d < 16; ++d) {
            float4 xa = *reinterpret_cast<const float4*>(&xT[d][tr * 8]);
            float4 xb = *reinterpret_cast<const float4*>(&xT[d][tr * 8 + 4]);
            float4 e0 = *reinterpret_cast<const float4*>(&eT[d][tc * 4]);
            float4 e1 = *reinterpret_cast<const float4*>(&eT[d][64 + tc * 4]);
            float xv[8] = {xa.x, xa.y, xa.z, xa.w, xb.x, xb.y, xb.z, xb.w};
            float ev[8] = {e0.x, e0.y, e0.z, e0.w, e1.x, e1.y, e1.z, e1.w};
            #pragma unroll
            for (int i = 0; i < 8; ++i)
                #pragma unroll
                for (int j = 0; j < 8; ++j)
                    acc[i][j] = fmaf(xv[i], ev[j], acc[i][j]);
        }
    }

    // epilogue: dist = ||e||^2 - 2 x.e  (x^2 dropped, row-constant)
    float best[8];
    int   bi[8];
    #pragma unroll
    for (int i = 0; i < 8; ++i) { best[i] = 3.4e38f; bi[i] = 0; }
    #pragma unroll
    for (int j = 0; j < 8; ++j) {
        int c = c0 + ((j < 4) ? (tc * 4 + j) : (64 + tc * 4 + (j - 4)));
        float e2 = en2[c];
        #pragma unroll
        for (int i = 0; i < 8; ++i) {
            float dist = fmaf(-2.f, acc[i][j], e2);
            if (dist < best[i] || (dist == best[i] && c < bi[i])) {
                best[i] = dist; bi[i] = c;
            }
        }
    }
    // reduce across the 16 lanes (same tr) holding disjoint code subsets
    #pragma unroll
    for (int off = 1; off < 16; off <<= 1) {
        #pragma unroll
        for (int i = 0; i < 8; ++i) {
            float ob = __shfl_xor(best[i], off);
            int   oi = __shfl_xor(bi[i], off);
            if (ob < best[i] || (ob == best[i] && oi < bi[i])) {
                best[i] = ob; bi[i] = oi;
            }
        }
    }
    if (tc == 0) {
        #pragma unroll
        for (int i = 0; i < 8; ++i) {
            unsigned ub = __float_as_uint(best[i]);
            ub = (ub & 0x80000000u) ? ~ub : (ub | 0x80000000u);
            unsigned long long key =
                ((unsigned long long)ub << 32) | (unsigned)bi[i];
            atomicMin(&packed[row0 + tr * 8 + i], key);
        }
    }
}

__global__ __launch_bounds__(256) void k_unpack(const unsigned long long* __restrict__ p,
                                                int* __restrict__ idx) {
    int g = blockIdx.x * 256 + threadIdx.x;
    idx[g] = (int)(unsigned)(p[g] & 0xFFFFFFFFull);
}

// ---------------- histogram of idx ----------------
__global__ __launch_bounds__(256) void k_hist(const int* __restrict__ idx,
                                              int* __restrict__ counts) {
    __shared__ int h[KC];
    for (int i = threadIdx.x; i < KC; i += 256) h[i] = 0;
    __syncthreads();
    int g = blockIdx.x * 256 + threadIdx.x;
    atomicAdd(&h[idx[g]], 1);
    __syncthreads();
    for (int i = threadIdx.x; i < KC; i += 256)
        if (h[i]) atomicAdd(&counts[i], h[i]);
}

// ---------------- smoothing, perplexity, prefix sums ----------------
__global__ __launch_bounds__(1024) void k_meta(const int* __restrict__ counts,
                                               const float* __restrict__ ema_cs,
                                               float* __restrict__ smoothed,
                                               int* __restrict__ offsets,
                                               int* __restrict__ cursor,
                                               float* __restrict__ perp_out) {
    __shared__ float red[KC];
    __shared__ int sc[KC];
    int t = threadIdx.x;
    int cnt = counts[t];
    float cs = ema_cs[t] * 0.99f + 0.01f * (float)cnt;
    red[t] = cs; __syncthreads();
    for (int s = 512; s; s >>= 1) { if (t < s) red[t] += red[t + s]; __syncthreads(); }
    float n = red[0];
    __syncthreads();
    float sm = (cs + 1e-5f) / (n + 1024.f * 1e-5f) * n;
    smoothed[t] = sm;
    float p = (float)cnt / 32768.f;
    red[t] = p * logf(p + 1e-10f);
    __syncthreads();
    for (int s = 512; s; s >>= 1) { if (t < s) red[t] += red[t + s]; __syncthreads(); }
    if (!t) perp_out[0] = expf(-red[0]);
    // exclusive prefix sum of counts
    sc[t] = cnt; __syncthreads();
    for (int s = 1; s < KC; s <<= 1) {
        int v = (t >= s) ? sc[t - s] : 0;
        __syncthreads();
        sc[t] += v;
        __syncthreads();
    }
    int off = sc[t] - cnt;
    offsets[t] = off;
    cursor[t] = off;
}

// ---------------- CSR bucket scatter ----------------
__global__ __launch_bounds__(256) void k_scatter(const int* __restrict__ idx,
                                                 int* __restrict__ cursor,
                                                 int* __restrict__ bucket) {
    int g = blockIdx.x * 256 + threadIdx.x;
    int c = idx[g];
    int pos = atomicAdd(&cursor[c], 1);
    bucket[pos] = g;
}

// ---------------- segment-sum + new embedding ----------------
__global__ __launch_bounds__(256) void k_dw(const float* __restrict__ x,
                                            const float* __restrict__ ema_w,
                                            const int* __restrict__ offsets,
                                            const int* __restrict__ counts,
                                            const int* __restrict__ bucket,
                                            const float* __restrict__ smoothed,
                                            float* __restrict__ newE) {
    int k = blockIdx.x, t = threadIdx.x;
    int beg = offsets[k], m = counts[k];
    float a0 = 0.f, a1 = 0.f;
    for (int i = 0; i < m; ++i) {
        int r = bucket[beg + i];
        a0 += x[(size_t)r * DIM + t];
        a1 += x[(size_t)r * DIM + t + 256];
    }
    float sm = smoothed[k];
    newE[(size_t)k * DIM + t]       = (ema_w[(size_t)k * DIM + t]       * 0.99f + 0.01f * a0) / sm;
    newE[(size_t)k * DIM + t + 256] = (ema_w[(size_t)k * DIM + t + 256] * 0.99f + 0.01f * a1) / sm;
}

// ---------------- quantized output (STE) + loss partials ----------------
__global__ __launch_bounds__(256) void k_quant(const float* __restrict__ x,
                                               const int* __restrict__ idx,
                                               const float* __restrict__ newE,
                                               float* __restrict__ outq,
                                               float* __restrict__ partials) {
    int t0 = blockIdx.x * 256 + threadIdx.x;   // 4096*256 = 1048576 threads
    float lp = 0.f;
    #pragma unroll 4
    for (int s = 0; s < 16; ++s) {
        int e = t0 + s * 1048576;
        int row = e >> 9;
        int c = idx[row];
        float in = x[e];
        float q = newE[(size_t)c * DIM + (e & 511)];
        float d = q - in;
        outq[e] = in + d;
        lp += d * d;
    }
    #pragma unroll
    for (int off = 32; off; off >>= 1) lp += __shfl_xor(lp, off);
    __shared__ float wr[4];
    int lane = threadIdx.x & 63, w = threadIdx.x >> 6;
    if (!lane) wr[w] = lp;
    __syncthreads();
    if (threadIdx.x == 0) partials[blockIdx.x] = wr[0] + wr[1] + wr[2] + wr[3];
}

__global__ __launch_bounds__(256) void k_lossfin(const float* __restrict__ partials,
                                                 float* __restrict__ out0) {
    __shared__ double red[256];
    double s = 0.0;
    for (int i = threadIdx.x; i < 4096; i += 256) s += (double)partials[i];
    red[threadIdx.x] = s; __syncthreads();
    for (int st = 128; st; st >>= 1) {
        if (threadIdx.x < st) red[threadIdx.x] += red[threadIdx.x + st];
        __syncthreads();
    }
    if (!threadIdx.x) out0[0] = (float)(0.25 * red[0] / 16777216.0);
}

// ---------------- one-hot encodings scatter ----------------
__global__ __launch_bounds__(256) void k_onehot(const int* __restrict__ idx,
                                                float* __restrict__ enc) {
    int g = blockIdx.x * 256 + threadIdx.x;
    enc[(size_t)g * KC + idx[g]] = 1.0f;
}

extern "C" void kernel_launch(void* const* d_in, const int* in_sizes, int n_in,
                              void* d_out, int out_size, void* d_ws, size_t ws_size,
                              hipStream_t stream) {
    const float* x   = (const float*)d_in[0];   // inputs [32,1024,512]
    const float* E   = (const float*)d_in[1];   // embedding_weight [1024,512]
    const float* ecs = (const float*)d_in[2];   // ema_cluster_size [1024]
    const float* emw = (const float*)d_in[3];   // ema_w [1024,512]
    float* out = (float*)d_out;

    char* ws = (char*)d_ws;
    int*   idx      = (int*)(ws + 0);                 // 128 KB
    int*   bucket   = (int*)(ws + 131072);            // 128 KB
    float* en2      = (float*)(ws + 262144);          // 4 KB
    int*   counts   = (int*)(ws + 266240);            // 4 KB
    int*   offsets  = (int*)(ws + 270336);            // 4 KB
    int*   cursor   = (int*)(ws + 274432);            // 4 KB
    float* smoothed = (float*)(ws + 278528);          // 4 KB
    float* newE     = (float*)(ws + 282624);          // 2 MB
    float* partials = (float*)(ws + 282624 + 2097152); // 16 KB
    // packed argmin keys alias newE's first 256 KB (newE is written later, by k_dw)
    unsigned long long* packed = (unsigned long long*)newE;

    float* out_loss = out;                  // [1]
    float* out_q    = out + 1;              // [16777216]
    float* out_perp = out + 16777217;       // [1]
    float* out_enc  = out + 16777218;       // [33554432]

    hipMemsetAsync(counts, 0, KC * sizeof(int), stream);
    hipMemsetAsync(packed, 0xFF, NROWS * sizeof(unsigned long long), stream);
    hipMemsetAsync(out_enc, 0, (size_t)NROWS * KC * sizeof(float), stream);

    k_enorm  <<<KC / 4, 256, 0, stream>>>(E, en2);
    k_argmin <<<(NROWS / 128) * 8, 256, 0, stream>>>(x, E, en2, packed);
    k_unpack <<<NROWS / 256, 256, 0, stream>>>(packed, idx);
    k_hist   <<<NROWS / 256, 256, 0, stream>>>(idx, counts);
    k_meta   <<<1, 1024, 0, stream>>>(counts, ecs, smoothed, offsets, cursor, out_perp);
    k_scatter<<<NROWS / 256, 256, 0, stream>>>(idx, cursor, bucket);
    k_dw     <<<KC, 256, 0, stream>>>(x, emw, offsets, counts, bucket, smoothed, newE);
    k_quant  <<<4096, 256, 0, stream>>>(x, idx, newE, out_q, partials);
    k_lossfin<<<1, 256, 0, stream>>>(partials, out_loss);
    k_onehot <<<NROWS / 256, 256, 0, stream>>>(idx, out_enc);
}

// Round 3
// 526.136 us; speedup vs baseline: 1.7491x; 1.5167x over previous
//
#include <hip/hip_runtime.h>

#define NROWS 32768
#define DIM   512
#define KC    1024

typedef __attribute__((ext_vector_type(8)))  short short8v;
typedef __attribute__((ext_vector_type(16))) float f32x16;

// ---------------- e_norm2: ||E[k]||^2 (exact fp32) ----------------
__global__ __launch_bounds__(256) void k_enorm(const float* __restrict__ E,
                                               float* __restrict__ en2) {
    int w = threadIdx.x >> 6, lane = threadIdx.x & 63;
    int c = blockIdx.x * 4 + w;
    const float* row = E + (size_t)c * DIM;
    float4 a = *reinterpret_cast<const float4*>(&row[lane * 8]);
    float4 b = *reinterpret_cast<const float4*>(&row[lane * 8 + 4]);
    float s = a.x*a.x + a.y*a.y + a.z*a.z + a.w*a.w
            + b.x*b.x + b.y*b.y + b.z*b.z + b.w*b.w;
    #pragma unroll
    for (int off = 32; off; off >>= 1) s += __shfl_xor(s, off);
    if (!lane) en2[c] = s;
}

// RTN float -> bf16(short), plus residual bf16
__device__ __forceinline__ void split_bf16(float v, short& hi, short& lo) {
    unsigned u = __float_as_uint(v);
    unsigned r = u + 0x7FFFu + ((u >> 16) & 1u);
    hi = (short)(r >> 16);
    float hif = __uint_as_float(r & 0xFFFF0000u);
    float rem = v - hif;
    unsigned u2 = __float_as_uint(rem);
    unsigned r2 = u2 + 0x7FFFu + ((u2 >> 16) & 1u);
    lo = (short)(r2 >> 16);
}

__device__ __forceinline__ unsigned long long pack_key(float d, int c) {
    unsigned u = __float_as_uint(d);
    u = (u & 0x80000000u) ? ~u : (u | 0x80000000u);   // monotone for min
    return ((unsigned long long)u << 32) | (unsigned)c;
}

// ---------------- argmin via split-bf16 MFMA distance GEMM ----------------
// tile 128 rows x 128 codes, BK=32, 4 waves (2x2), wave = 2x2 mfma 32x32x16.
// grid 2048; XCD-chunked mapping: xcd k gets row-tiles [k*32,(k+1)*32) x all
// 8 code-splits consecutively -> x-tile + whole E stay in that XCD's L2.
__global__ __launch_bounds__(256, 2) void k_argmin(const float* __restrict__ x,
                                                   const float* __restrict__ E,
                                                   const float* __restrict__ en2,
                                                   unsigned long long* __restrict__ packed) {
    __shared__ short xhi[128][48], xlo[128][48];   // stride 48: 16B-aligned rows,
    __shared__ short ehi[128][48], elo[128][48];   // 2-way-free b128 frag reads
    const int tid = threadIdx.x;
    const int w = tid >> 6, l = tid & 63;
    const int wr = w >> 1, wc = w & 1;
    const int l31 = l & 31, lh = l >> 5;

    int bid = blockIdx.x;                // 2048 blocks
    int xcd = bid & 7, j = bid >> 3;     // dispatch round-robins bid%8 over XCDs
    int row0 = (xcd * 32 + (j >> 3)) * 128;
    int c0   = (j & 7) * 128;

    f32x16 acc[2][2];
    #pragma unroll
    for (int a = 0; a < 2; ++a)
        #pragma unroll
        for (int b = 0; b < 2; ++b)
            #pragma unroll
            for (int r = 0; r < 16; ++r) acc[a][b][r] = 0.f;

    float4 rx[4], re[4];
    // prologue loads (dt=0)
    #pragma unroll
    for (int h = 0; h < 4; ++h) {
        int s = tid + h * 256, r = s >> 3, f4 = s & 7;
        rx[h] = *reinterpret_cast<const float4*>(&x[(size_t)(row0 + r) * DIM + f4 * 4]);
        re[h] = *reinterpret_cast<const float4*>(&E[(size_t)(c0   + r) * DIM + f4 * 4]);
    }

    for (int dt = 0; dt < DIM; dt += 32) {
        __syncthreads();
        #pragma unroll
        for (int h = 0; h < 4; ++h) {
            int s = tid + h * 256, r = s >> 3, f4 = s & 7;
            short4 h4, l4;
            split_bf16(rx[h].x, h4.x, l4.x); split_bf16(rx[h].y, h4.y, l4.y);
            split_bf16(rx[h].z, h4.z, l4.z); split_bf16(rx[h].w, h4.w, l4.w);
            *reinterpret_cast<short4*>(&xhi[r][f4 * 4]) = h4;
            *reinterpret_cast<short4*>(&xlo[r][f4 * 4]) = l4;
            split_bf16(re[h].x, h4.x, l4.x); split_bf16(re[h].y, h4.y, l4.y);
            split_bf16(re[h].z, h4.z, l4.z); split_bf16(re[h].w, h4.w, l4.w);
            *reinterpret_cast<short4*>(&ehi[r][f4 * 4]) = h4;
            *reinterpret_cast<short4*>(&elo[r][f4 * 4]) = l4;
        }
        __syncthreads();
        if (dt + 32 < DIM) {
            #pragma unroll
            for (int h = 0; h < 4; ++h) {
                int s = tid + h * 256, r = s >> 3, f4 = s & 7;
                rx[h] = *reinterpret_cast<const float4*>(
                    &x[(size_t)(row0 + r) * DIM + dt + 32 + f4 * 4]);
                re[h] = *reinterpret_cast<const float4*>(
                    &E[(size_t)(c0   + r) * DIM + dt + 32 + f4 * 4]);
            }
        }
        #pragma unroll
        for (int ks = 0; ks < 2; ++ks) {
            const int kb = ks * 16 + lh * 8;
            short8v axh[2], axl[2], beh[2], bel[2];
            #pragma unroll
            for (int tm = 0; tm < 2; ++tm) {
                int row = wr * 64 + tm * 32 + l31;
                axh[tm] = *reinterpret_cast<const short8v*>(&xhi[row][kb]);
                axl[tm] = *reinterpret_cast<const short8v*>(&xlo[row][kb]);
            }
            #pragma unroll
            for (int tn = 0; tn < 2; ++tn) {
                int col = wc * 64 + tn * 32 + l31;
                beh[tn] = *reinterpret_cast<const short8v*>(&ehi[col][kb]);
                bel[tn] = *reinterpret_cast<const short8v*>(&elo[col][kb]);
            }
            #pragma unroll
            for (int tm = 0; tm < 2; ++tm)
                #pragma unroll
                for (int tn = 0; tn < 2; ++tn) {
                    acc[tm][tn] = __builtin_amdgcn_mfma_f32_32x32x16_bf16(
                        axh[tm], beh[tn], acc[tm][tn], 0, 0, 0);
                    acc[tm][tn] = __builtin_amdgcn_mfma_f32_32x32x16_bf16(
                        axh[tm], bel[tn], acc[tm][tn], 0, 0, 0);
                    acc[tm][tn] = __builtin_amdgcn_mfma_f32_32x32x16_bf16(
                        axl[tm], beh[tn], acc[tm][tn], 0, 0, 0);
                }
        }
    }

    // epilogue: dist = ||e||^2 - 2 x.e ; D layout: col=l&31,
    // row=(r&3)+8*(r>>2)+4*(l>>5)
    float e2[2];
    #pragma unroll
    for (int tn = 0; tn < 2; ++tn) e2[tn] = en2[c0 + wc * 64 + tn * 32 + l31];
    const int cA = c0 + wc * 64 + l31;
    #pragma unroll
    for (int tm = 0; tm < 2; ++tm) {
        #pragma unroll
        for (int r = 0; r < 16; ++r) {
            float d0 = fmaf(-2.f, acc[tm][0][r], e2[0]);
            float d1 = fmaf(-2.f, acc[tm][1][r], e2[1]);
            unsigned long long k0 = pack_key(d0, cA);
            unsigned long long k1 = pack_key(d1, cA + 32);
            unsigned long long key = k0 < k1 ? k0 : k1;
            #pragma unroll
            for (int off = 1; off < 32; off <<= 1) {
                unsigned long long o = __shfl_xor(key, off);
                if (o < key) key = o;
            }
            if (l31 == 0) {
                int grow = row0 + wr * 64 + tm * 32 + (r & 3) + 8 * (r >> 2) + 4 * lh;
                atomicMin(&packed[grow], key);
            }
        }
    }
}

// ---------------- unpack idx + histogram ----------------
__global__ __launch_bounds__(256) void k_hist(const unsigned long long* __restrict__ packed,
                                              int* __restrict__ idx,
                                              int* __restrict__ counts) {
    __shared__ int h[KC];
    for (int i = threadIdx.x; i < KC; i += 256) h[i] = 0;
    __syncthreads();
    int g = blockIdx.x * 256 + threadIdx.x;
    int c = (int)(unsigned)(packed[g] & 0xFFFFFFFFull);
    idx[g] = c;
    atomicAdd(&h[c], 1);
    __syncthreads();
    for (int i = threadIdx.x; i < KC; i += 256)
        if (h[i]) atomicAdd(&counts[i], h[i]);
}

// ---------------- smoothing, perplexity, prefix sums ----------------
__global__ __launch_bounds__(1024) void k_meta(const int* __restrict__ counts,
                                               const float* __restrict__ ema_cs,
                                               float* __restrict__ smoothed,
                                               int* __restrict__ offsets,
                                               int* __restrict__ cursor,
                                               float* __restrict__ perp_out) {
    __shared__ float red[KC];
    __shared__ int sc[KC];
    int t = threadIdx.x;
    int cnt = counts[t];
    float cs = ema_cs[t] * 0.99f + 0.01f * (float)cnt;
    red[t] = cs; __syncthreads();
    for (int s = 512; s; s >>= 1) { if (t < s) red[t] += red[t + s]; __syncthreads(); }
    float n = red[0];
    __syncthreads();
    float sm = (cs + 1e-5f) / (n + 1024.f * 1e-5f) * n;
    smoothed[t] = sm;
    float p = (float)cnt / 32768.f;
    red[t] = p * logf(p + 1e-10f);
    __syncthreads();
    for (int s = 512; s; s >>= 1) { if (t < s) red[t] += red[t + s]; __syncthreads(); }
    if (!t) perp_out[0] = expf(-red[0]);
    sc[t] = cnt; __syncthreads();
    for (int s = 1; s < KC; s <<= 1) {
        int v = (t >= s) ? sc[t - s] : 0;
        __syncthreads();
        sc[t] += v;
        __syncthreads();
    }
    int off = sc[t] - cnt;
    offsets[t] = off;
    cursor[t] = off;
}

// ---------------- CSR bucket scatter ----------------
__global__ __launch_bounds__(256) void k_scatter(const int* __restrict__ idx,
                                                 int* __restrict__ cursor,
                                                 int* __restrict__ bucket) {
    int g = blockIdx.x * 256 + threadIdx.x;
    int c = idx[g];
    int pos = atomicAdd(&cursor[c], 1);
    bucket[pos] = g;
}

// ---------------- one-hot encodings: full-row writer ----------------
__global__ __launch_bounds__(256) void k_enc(const int* __restrict__ idx,
                                             float* __restrict__ enc) {
    int t = threadIdx.x;
    int row = blockIdx.x * 8 + (t >> 5);
    int l32 = t & 31;
    int one = idx[row];
    float4* dst = reinterpret_cast<float4*>(enc + (size_t)row * KC);
    #pragma unroll
    for (int s = 0; s < 8; ++s) {
        int c4 = l32 + s * 32;
        int base = c4 * 4;
        float4 v;
        v.x = (one == base)     ? 1.f : 0.f;
        v.y = (one == base + 1) ? 1.f : 0.f;
        v.z = (one == base + 2) ? 1.f : 0.f;
        v.w = (one == base + 3) ? 1.f : 0.f;
        dst[c4] = v;
    }
}

// ---------------- segment-sum + new embedding ----------------
__global__ __launch_bounds__(256) void k_dw(const float* __restrict__ x,
                                            const float* __restrict__ ema_w,
                                            const int* __restrict__ offsets,
                                            const int* __restrict__ counts,
                                            const int* __restrict__ bucket,
                                            const float* __restrict__ smoothed,
                                            float* __restrict__ newE) {
    int k = blockIdx.x, t = threadIdx.x;
    int beg = offsets[k], m = counts[k];
    float a0 = 0.f, a1 = 0.f;
    for (int i = 0; i < m; ++i) {
        int r = bucket[beg + i];
        a0 += x[(size_t)r * DIM + t];
        a1 += x[(size_t)r * DIM + t + 256];
    }
    float sm = smoothed[k];
    newE[(size_t)k * DIM + t]       = (ema_w[(size_t)k * DIM + t]       * 0.99f + 0.01f * a0) / sm;
    newE[(size_t)k * DIM + t + 256] = (ema_w[(size_t)k * DIM + t + 256] * 0.99f + 0.01f * a1) / sm;
}

// ---------------- quantized output (STE) + loss partials ----------------
__global__ __launch_bounds__(256) void k_quant(const float* __restrict__ x,
                                               const int* __restrict__ idx,
                                               const float* __restrict__ newE,
                                               float* __restrict__ outq,
                                               float* __restrict__ partials) {
    int t0 = blockIdx.x * 256 + threadIdx.x;
    float lp = 0.f;
    #pragma unroll 4
    for (int s = 0; s < 16; ++s) {
        int e = t0 + s * 1048576;
        int row = e >> 9;
        int c = idx[row];
        float in = x[e];
        float q = newE[(size_t)c * DIM + (e & 511)];
        float d = q - in;
        outq[e] = in + d;
        lp += d * d;
    }
    #pragma unroll
    for (int off = 32; off; off >>= 1) lp += __shfl_xor(lp, off);
    __shared__ float wr[4];
    int lane = threadIdx.x & 63, w = threadIdx.x >> 6;
    if (!lane) wr[w] = lp;
    __syncthreads();
    if (threadIdx.x == 0) partials[blockIdx.x] = wr[0] + wr[1] + wr[2] + wr[3];
}

__global__ __launch_bounds__(256) void k_lossfin(const float* __restrict__ partials,
                                                 float* __restrict__ out0) {
    __shared__ double red[256];
    double s = 0.0;
    for (int i = threadIdx.x; i < 4096; i += 256) s += (double)partials[i];
    red[threadIdx.x] = s; __syncthreads();
    for (int st = 128; st; st >>= 1) {
        if (threadIdx.x < st) red[threadIdx.x] += red[threadIdx.x + st];
        __syncthreads();
    }
    if (!threadIdx.x) out0[0] = (float)(0.25 * red[0] / 16777216.0);
}

extern "C" void kernel_launch(void* const* d_in, const int* in_sizes, int n_in,
                              void* d_out, int out_size, void* d_ws, size_t ws_size,
                              hipStream_t stream) {
    const float* x   = (const float*)d_in[0];
    const float* E   = (const float*)d_in[1];
    const float* ecs = (const float*)d_in[2];
    const float* emw = (const float*)d_in[3];
    float* out = (float*)d_out;

    char* ws = (char*)d_ws;
    int*   idx      = (int*)(ws + 0);                  // 128 KB
    int*   bucket   = (int*)(ws + 131072);             // 128 KB
    float* en2      = (float*)(ws + 262144);           // 4 KB
    int*   counts   = (int*)(ws + 266240);             // 4 KB
    int*   offsets  = (int*)(ws + 270336);             // 4 KB
    int*   cursor   = (int*)(ws + 274432);             // 4 KB
    float* smoothed = (float*)(ws + 278528);           // 4 KB
    float* newE     = (float*)(ws + 282624);           // 2 MB
    float* partials = (float*)(ws + 282624 + 2097152); // 16 KB
    unsigned long long* packed = (unsigned long long*)newE;  // dead before k_dw

    float* out_loss = out;
    float* out_q    = out + 1;
    float* out_perp = out + 16777217;
    float* out_enc  = out + 16777218;

    hipMemsetAsync(counts, 0, KC * sizeof(int), stream);
    hipMemsetAsync(packed, 0xFF, NROWS * sizeof(unsigned long long), stream);

    k_enorm  <<<KC / 4, 256, 0, stream>>>(E, en2);
    k_argmin <<<(NROWS / 128) * 8, 256, 0, stream>>>(x, E, en2, packed);
    k_hist   <<<NROWS / 256, 256, 0, stream>>>(packed, idx, counts);
    k_meta   <<<1, 1024, 0, stream>>>(counts, ecs, smoothed, offsets, cursor, out_perp);
    k_scatter<<<NROWS / 256, 256, 0, stream>>>(idx, cursor, bucket);
    k_enc    <<<NROWS / 8, 256, 0, stream>>>(idx, out_enc);
    k_dw     <<<KC, 256, 0, stream>>>(x, emw, offsets, counts, bucket, smoothed, newE);
    k_quant  <<<4096, 256, 0, stream>>>(x, idx, newE, out_q, partials);
    k_lossfin<<<1, 256, 0, stream>>>(partials, out_loss);
}

// Round 4
// 346.706 us; speedup vs baseline: 2.6543x; 1.5175x over previous
//
#include <hip/hip_runtime.h>

#define NROWS 32768
#define DIM   512
#define KC    1024

typedef __attribute__((ext_vector_type(8)))  short short8v;
typedef __attribute__((ext_vector_type(16))) float f32x16;

// ---------------- e_norm2: ||E[k]||^2 (exact fp32) ----------------
__global__ __launch_bounds__(256) void k_enorm(const float* __restrict__ E,
                                               float* __restrict__ en2) {
    int w = threadIdx.x >> 6, lane = threadIdx.x & 63;
    int c = blockIdx.x * 4 + w;
    const float* row = E + (size_t)c * DIM;
    float4 a = *reinterpret_cast<const float4*>(&row[lane * 8]);
    float4 b = *reinterpret_cast<const float4*>(&row[lane * 8 + 4]);
    float s = a.x*a.x + a.y*a.y + a.z*a.z + a.w*a.w
            + b.x*b.x + b.y*b.y + b.z*b.z + b.w*b.w;
    #pragma unroll
    for (int off = 32; off; off >>= 1) s += __shfl_xor(s, off);
    if (!lane) en2[c] = s;
}

// RTN float -> bf16(short), plus residual bf16
__device__ __forceinline__ void split_bf16(float v, short& hi, short& lo) {
    unsigned u = __float_as_uint(v);
    unsigned r = u + 0x7FFFu + ((u >> 16) & 1u);
    hi = (short)(r >> 16);
    float hif = __uint_as_float(r & 0xFFFF0000u);
    float rem = v - hif;
    unsigned u2 = __float_as_uint(rem);
    unsigned r2 = u2 + 0x7FFFu + ((u2 >> 16) & 1u);
    lo = (short)(r2 >> 16);
}

__device__ __forceinline__ unsigned long long pack_key(float d, int c) {
    unsigned u = __float_as_uint(d);
    u = (u & 0x80000000u) ? ~u : (u | 0x80000000u);   // monotone for min
    return ((unsigned long long)u << 32) | (unsigned)c;
}

// ---------------- argmin via split-bf16 MFMA distance GEMM ----------------
// tile 128 rows x 128 codes, BK=32, 4 waves (2x2), wave = 2x2 mfma 32x32x16.
// grid 2048; XCD-chunked mapping: xcd k gets row-tiles [k*32,(k+1)*32) x all
// 8 code-splits consecutively -> x-tile + whole E stay in that XCD's L2.
__global__ __launch_bounds__(256, 2) void k_argmin(const float* __restrict__ x,
                                                   const float* __restrict__ E,
                                                   const float* __restrict__ en2,
                                                   unsigned long long* __restrict__ packed) {
    __shared__ short xhi[128][48], xlo[128][48];   // stride 48: 16B-aligned rows,
    __shared__ short ehi[128][48], elo[128][48];   // 2-way-free b128 frag reads
    const int tid = threadIdx.x;
    const int w = tid >> 6, l = tid & 63;
    const int wr = w >> 1, wc = w & 1;
    const int l31 = l & 31, lh = l >> 5;

    int bid = blockIdx.x;                // 2048 blocks
    int xcd = bid & 7, j = bid >> 3;     // dispatch round-robins bid%8 over XCDs
    int row0 = (xcd * 32 + (j >> 3)) * 128;
    int c0   = (j & 7) * 128;

    f32x16 acc[2][2];
    #pragma unroll
    for (int a = 0; a < 2; ++a)
        #pragma unroll
        for (int b = 0; b < 2; ++b)
            #pragma unroll
            for (int r = 0; r < 16; ++r) acc[a][b][r] = 0.f;

    float4 rx[4], re[4];
    // prologue loads (dt=0)
    #pragma unroll
    for (int h = 0; h < 4; ++h) {
        int s = tid + h * 256, r = s >> 3, f4 = s & 7;
        rx[h] = *reinterpret_cast<const float4*>(&x[(size_t)(row0 + r) * DIM + f4 * 4]);
        re[h] = *reinterpret_cast<const float4*>(&E[(size_t)(c0   + r) * DIM + f4 * 4]);
    }

    for (int dt = 0; dt < DIM; dt += 32) {
        __syncthreads();
        #pragma unroll
        for (int h = 0; h < 4; ++h) {
            int s = tid + h * 256, r = s >> 3, f4 = s & 7;
            short4 h4, l4;
            split_bf16(rx[h].x, h4.x, l4.x); split_bf16(rx[h].y, h4.y, l4.y);
            split_bf16(rx[h].z, h4.z, l4.z); split_bf16(rx[h].w, h4.w, l4.w);
            *reinterpret_cast<short4*>(&xhi[r][f4 * 4]) = h4;
            *reinterpret_cast<short4*>(&xlo[r][f4 * 4]) = l4;
            split_bf16(re[h].x, h4.x, l4.x); split_bf16(re[h].y, h4.y, l4.y);
            split_bf16(re[h].z, h4.z, l4.z); split_bf16(re[h].w, h4.w, l4.w);
            *reinterpret_cast<short4*>(&ehi[r][f4 * 4]) = h4;
            *reinterpret_cast<short4*>(&elo[r][f4 * 4]) = l4;
        }
        __syncthreads();
        if (dt + 32 < DIM) {
            #pragma unroll
            for (int h = 0; h < 4; ++h) {
                int s = tid + h * 256, r = s >> 3, f4 = s & 7;
                rx[h] = *reinterpret_cast<const float4*>(
                    &x[(size_t)(row0 + r) * DIM + dt + 32 + f4 * 4]);
                re[h] = *reinterpret_cast<const float4*>(
                    &E[(size_t)(c0   + r) * DIM + dt + 32 + f4 * 4]);
            }
        }
        #pragma unroll
        for (int ks = 0; ks < 2; ++ks) {
            const int kb = ks * 16 + lh * 8;
            short8v axh[2], axl[2], beh[2], bel[2];
            #pragma unroll
            for (int tm = 0; tm < 2; ++tm) {
                int row = wr * 64 + tm * 32 + l31;
                axh[tm] = *reinterpret_cast<const short8v*>(&xhi[row][kb]);
                axl[tm] = *reinterpret_cast<const short8v*>(&xlo[row][kb]);
            }
            #pragma unroll
            for (int tn = 0; tn < 2; ++tn) {
                int col = wc * 64 + tn * 32 + l31;
                beh[tn] = *reinterpret_cast<const short8v*>(&ehi[col][kb]);
                bel[tn] = *reinterpret_cast<const short8v*>(&elo[col][kb]);
            }
            #pragma unroll
            for (int tm = 0; tm < 2; ++tm)
                #pragma unroll
                for (int tn = 0; tn < 2; ++tn) {
                    acc[tm][tn] = __builtin_amdgcn_mfma_f32_32x32x16_bf16(
                        axh[tm], beh[tn], acc[tm][tn], 0, 0, 0);
                    acc[tm][tn] = __builtin_amdgcn_mfma_f32_32x32x16_bf16(
                        axh[tm], bel[tn], acc[tm][tn], 0, 0, 0);
                    acc[tm][tn] = __builtin_amdgcn_mfma_f32_32x32x16_bf16(
                        axl[tm], beh[tn], acc[tm][tn], 0, 0, 0);
                }
        }
    }

    // epilogue: dist = ||e||^2 - 2 x.e ; D layout: col=l&31,
    // row=(r&3)+8*(r>>2)+4*(l>>5)
    float e2[2];
    #pragma unroll
    for (int tn = 0; tn < 2; ++tn) e2[tn] = en2[c0 + wc * 64 + tn * 32 + l31];
    const int cA = c0 + wc * 64 + l31;
    #pragma unroll
    for (int tm = 0; tm < 2; ++tm) {
        #pragma unroll
        for (int r = 0; r < 16; ++r) {
            float d0 = fmaf(-2.f, acc[tm][0][r], e2[0]);
            float d1 = fmaf(-2.f, acc[tm][1][r], e2[1]);
            unsigned long long k0 = pack_key(d0, cA);
            unsigned long long k1 = pack_key(d1, cA + 32);
            unsigned long long key = k0 < k1 ? k0 : k1;
            #pragma unroll
            for (int off = 1; off < 32; off <<= 1) {
                unsigned long long o = __shfl_xor(key, off);
                if (o < key) key = o;
            }
            if (l31 == 0) {
                int grow = row0 + wr * 64 + tm * 32 + (r & 3) + 8 * (r >> 2) + 4 * lh;
                atomicMin(&packed[grow], key);
            }
        }
    }
}

// ---------------- unpack idx + histogram ----------------
__global__ __launch_bounds__(256) void k_hist(const unsigned long long* __restrict__ packed,
                                              int* __restrict__ idx,
                                              int* __restrict__ counts) {
    __shared__ int h[KC];
    for (int i = threadIdx.x; i < KC; i += 256) h[i] = 0;
    __syncthreads();
    int g = blockIdx.x * 256 + threadIdx.x;
    int c = (int)(unsigned)(packed[g] & 0xFFFFFFFFull);
    idx[g] = c;
    atomicAdd(&h[c], 1);
    __syncthreads();
    for (int i = threadIdx.x; i < KC; i += 256)
        if (h[i]) atomicAdd(&counts[i], h[i]);
}

// ---------------- smoothing, perplexity, prefix sums ----------------
__global__ __launch_bounds__(1024) void k_meta(const int* __restrict__ counts,
                                               const float* __restrict__ ema_cs,
                                               float* __restrict__ smoothed,
                                               int* __restrict__ offsets,
                                               int* __restrict__ cursor,
                                               float* __restrict__ perp_out) {
    __shared__ float red[KC];
    __shared__ int sc[KC];
    int t = threadIdx.x;
    int cnt = counts[t];
    float cs = ema_cs[t] * 0.99f + 0.01f * (float)cnt;
    red[t] = cs; __syncthreads();
    for (int s = 512; s; s >>= 1) { if (t < s) red[t] += red[t + s]; __syncthreads(); }
    float n = red[0];
    __syncthreads();
    float sm = (cs + 1e-5f) / (n + 1024.f * 1e-5f) * n;
    smoothed[t] = sm;
    float p = (float)cnt / 32768.f;
    red[t] = p * logf(p + 1e-10f);
    __syncthreads();
    for (int s = 512; s; s >>= 1) { if (t < s) red[t] += red[t + s]; __syncthreads(); }
    if (!t) perp_out[0] = expf(-red[0]);
    sc[t] = cnt; __syncthreads();
    for (int s = 1; s < KC; s <<= 1) {
        int v = (t >= s) ? sc[t - s] : 0;
        __syncthreads();
        sc[t] += v;
        __syncthreads();
    }
    int off = sc[t] - cnt;
    offsets[t] = off;
    cursor[t] = off;
}

// ---------------- CSR bucket scatter ----------------
__global__ __launch_bounds__(256) void k_scatter(const int* __restrict__ idx,
                                                 int* __restrict__ cursor,
                                                 int* __restrict__ bucket) {
    int g = blockIdx.x * 256 + threadIdx.x;
    int c = idx[g];
    int pos = atomicAdd(&cursor[c], 1);
    bucket[pos] = g;
}

// ---------------- one-hot encodings: full-row writer ----------------
__global__ __launch_bounds__(256) void k_enc(const int* __restrict__ idx,
                                             float* __restrict__ enc) {
    int t = threadIdx.x;
    int row = blockIdx.x * 8 + (t >> 5);
    int l32 = t & 31;
    int one = idx[row];
    float4* dst = reinterpret_cast<float4*>(enc + (size_t)row * KC);
    #pragma unroll
    for (int s = 0; s < 8; ++s) {
        int c4 = l32 + s * 32;
        int base = c4 * 4;
        float4 v;
        v.x = (one == base)     ? 1.f : 0.f;
        v.y = (one == base + 1) ? 1.f : 0.f;
        v.z = (one == base + 2) ? 1.f : 0.f;
        v.w = (one == base + 3) ? 1.f : 0.f;
        dst[c4] = v;
    }
}

// ---------------- segment-sum + new embedding (LDS-staged, unrolled) ------
// rows for this code staged in LDS chunks -> gather addresses independent,
// 8 coalesced loads in flight per thread.
__global__ __launch_bounds__(256) void k_dw(const float* __restrict__ x,
                                            const float* __restrict__ ema_w,
                                            const int* __restrict__ offsets,
                                            const int* __restrict__ counts,
                                            const int* __restrict__ bucket,
                                            const float* __restrict__ smoothed,
                                            float* __restrict__ newE) {
    __shared__ int rows[256];
    int k = blockIdx.x, t = threadIdx.x;
    int beg = offsets[k], m = counts[k];
    float a0 = 0.f, a1 = 0.f;
    for (int base = 0; base < m; base += 256) {
        int n = min(256, m - base);
        __syncthreads();
        if (t < n) rows[t] = bucket[beg + base + t];
        __syncthreads();
        int i = 0;
        for (; i + 4 <= n; i += 4) {
            int r0 = rows[i], r1 = rows[i + 1], r2 = rows[i + 2], r3 = rows[i + 3];
            float v00 = x[(size_t)r0 * DIM + t];
            float v01 = x[(size_t)r0 * DIM + t + 256];
            float v10 = x[(size_t)r1 * DIM + t];
            float v11 = x[(size_t)r1 * DIM + t + 256];
            float v20 = x[(size_t)r2 * DIM + t];
            float v21 = x[(size_t)r2 * DIM + t + 256];
            float v30 = x[(size_t)r3 * DIM + t];
            float v31 = x[(size_t)r3 * DIM + t + 256];
            a0 += v00 + v10 + v20 + v30;
            a1 += v01 + v11 + v21 + v31;
        }
        for (; i < n; ++i) {
            int r = rows[i];
            a0 += x[(size_t)r * DIM + t];
            a1 += x[(size_t)r * DIM + t + 256];
        }
    }
    float sm = smoothed[k];
    newE[(size_t)k * DIM + t]       = (ema_w[(size_t)k * DIM + t]       * 0.99f + 0.01f * a0) / sm;
    newE[(size_t)k * DIM + t + 256] = (ema_w[(size_t)k * DIM + t + 256] * 0.99f + 0.01f * a1) / sm;
}

// ---------------- quantized output (STE) + loss partials ----------------
__global__ __launch_bounds__(256) void k_quant(const float* __restrict__ x,
                                               const int* __restrict__ idx,
                                               const float* __restrict__ newE,
                                               float* __restrict__ outq,
                                               float* __restrict__ partials) {
    int t0 = blockIdx.x * 256 + threadIdx.x;
    float lp = 0.f;
    #pragma unroll 4
    for (int s = 0; s < 16; ++s) {
        int e = t0 + s * 1048576;
        int row = e >> 9;
        int c = idx[row];
        float in = x[e];
        float q = newE[(size_t)c * DIM + (e & 511)];
        float d = q - in;
        outq[e] = in + d;
        lp += d * d;
    }
    #pragma unroll
    for (int off = 32; off; off >>= 1) lp += __shfl_xor(lp, off);
    __shared__ float wr[4];
    int lane = threadIdx.x & 63, w = threadIdx.x >> 6;
    if (!lane) wr[w] = lp;
    __syncthreads();
    if (threadIdx.x == 0) partials[blockIdx.x] = wr[0] + wr[1] + wr[2] + wr[3];
}

__global__ __launch_bounds__(256) void k_lossfin(const float* __restrict__ partials,
                                                 float* __restrict__ out0) {
    __shared__ double red[256];
    double s = 0.0;
    for (int i = threadIdx.x; i < 4096; i += 256) s += (double)partials[i];
    red[threadIdx.x] = s; __syncthreads();
    for (int st = 128; st; st >>= 1) {
        if (threadIdx.x < st) red[threadIdx.x] += red[threadIdx.x + st];
        __syncthreads();
    }
    if (!threadIdx.x) out0[0] = (float)(0.25 * red[0] / 16777216.0);
}

extern "C" void kernel_launch(void* const* d_in, const int* in_sizes, int n_in,
                              void* d_out, int out_size, void* d_ws, size_t ws_size,
                              hipStream_t stream) {
    const float* x   = (const float*)d_in[0];
    const float* E   = (const float*)d_in[1];
    const float* ecs = (const float*)d_in[2];
    const float* emw = (const float*)d_in[3];
    float* out = (float*)d_out;

    char* ws = (char*)d_ws;
    int*   idx      = (int*)(ws + 0);                  // 128 KB
    int*   bucket   = (int*)(ws + 131072);             // 128 KB
    float* en2      = (float*)(ws + 262144);           // 4 KB
    int*   counts   = (int*)(ws + 266240);             // 4 KB
    int*   offsets  = (int*)(ws + 270336);             // 4 KB
    int*   cursor   = (int*)(ws + 274432);             // 4 KB
    float* smoothed = (float*)(ws + 278528);           // 4 KB
    float* newE     = (float*)(ws + 282624);           // 2 MB
    float* partials = (float*)(ws + 282624 + 2097152); // 16 KB
    unsigned long long* packed = (unsigned long long*)newE;  // dead before k_dw

    float* out_loss = out;
    float* out_q    = out + 1;
    float* out_perp = out + 16777217;
    float* out_enc  = out + 16777218;

    hipMemsetAsync(counts, 0, KC * sizeof(int), stream);
    hipMemsetAsync(packed, 0xFF, NROWS * sizeof(unsigned long long), stream);

    k_enorm  <<<KC / 4, 256, 0, stream>>>(E, en2);
    k_argmin <<<(NROWS / 128) * 8, 256, 0, stream>>>(x, E, en2, packed);
    k_hist   <<<NROWS / 256, 256, 0, stream>>>(packed, idx, counts);
    k_meta   <<<1, 1024, 0, stream>>>(counts, ecs, smoothed, offsets, cursor, out_perp);
    k_scatter<<<NROWS / 256, 256, 0, stream>>>(idx, cursor, bucket);
    k_enc    <<<NROWS / 8, 256, 0, stream>>>(idx, out_enc);
    k_dw     <<<KC, 256, 0, stream>>>(x, emw, offsets, counts, bucket, smoothed, newE);
    k_quant  <<<4096, 256, 0, stream>>>(x, idx, newE, out_q, partials);
    k_lossfin<<<1, 256, 0, stream>>>(partials, out_loss);
}

// Round 5
// 340.713 us; speedup vs baseline: 2.7010x; 1.0176x over previous
//
#include <hip/hip_runtime.h>

#define NROWS 32768
#define DIM   512
#define KC    1024

typedef __attribute__((ext_vector_type(8)))  short short8v;
typedef __attribute__((ext_vector_type(16))) float f32x16;

// ---------------- e_norm2: ||E[k]||^2 (exact fp32) ----------------
__global__ __launch_bounds__(256) void k_enorm(const float* __restrict__ E,
                                               float* __restrict__ en2) {
    int w = threadIdx.x >> 6, lane = threadIdx.x & 63;
    int c = blockIdx.x * 4 + w;
    const float* row = E + (size_t)c * DIM;
    float4 a = *reinterpret_cast<const float4*>(&row[lane * 8]);
    float4 b = *reinterpret_cast<const float4*>(&row[lane * 8 + 4]);
    float s = a.x*a.x + a.y*a.y + a.z*a.z + a.w*a.w
            + b.x*b.x + b.y*b.y + b.z*b.z + b.w*b.w;
    #pragma unroll
    for (int off = 32; off; off >>= 1) s += __shfl_xor(s, off);
    if (!lane) en2[c] = s;
}

// RTN float -> bf16(short), plus residual bf16
__device__ __forceinline__ void split_bf16(float v, short& hi, short& lo) {
    unsigned u = __float_as_uint(v);
    unsigned r = u + 0x7FFFu + ((u >> 16) & 1u);
    hi = (short)(r >> 16);
    float hif = __uint_as_float(r & 0xFFFF0000u);
    float rem = v - hif;
    unsigned u2 = __float_as_uint(rem);
    unsigned r2 = u2 + 0x7FFFu + ((u2 >> 16) & 1u);
    lo = (short)(r2 >> 16);
}

__device__ __forceinline__ unsigned long long pack_key(float d, int c) {
    unsigned u = __float_as_uint(d);
    u = (u & 0x80000000u) ? ~u : (u | 0x80000000u);   // monotone for min
    return ((unsigned long long)u << 32) | (unsigned)c;
}

// ---------------- split x and E to bf16 hi/lo in MFMA fragment layout -----
// layout per 32-row group r5: [kb 0..31][h 0..1][lane 0..63][8 shorts]
// fragment: lane l holds rows l&31, k = kb*16 + (l>>5)*8 .. +7
__global__ __launch_bounds__(256) void k_split(const float* __restrict__ x,
                                               const float* __restrict__ E,
                                               short* __restrict__ xfrag,
                                               short* __restrict__ efrag) {
    __shared__ short hbuf[32][520];   // pad 8: row stride 1040B (16B-aligned,
    __shared__ short lbuf[32][520];   // 4-way on phase-2 reads -- cheap)
    int b = blockIdx.x, t = threadIdx.x;
    const float* src;
    short* dst;
    if (b < NROWS / 32) {
        src = x + (size_t)b * 32 * DIM;
        dst = xfrag + (size_t)b * 32768;
    } else {
        src = E + (size_t)(b - NROWS / 32) * 32 * DIM;
        dst = efrag + (size_t)(b - NROWS / 32) * 32768;
    }
    #pragma unroll
    for (int f = 0; f < 16; ++f) {
        int u = t + f * 256;                  // float4 slots over [32][128]
        int row = u >> 7, c4 = (u & 127) * 4;
        float4 v = *reinterpret_cast<const float4*>(&src[row * DIM + c4]);
        short4 h4, l4;
        split_bf16(v.x, h4.x, l4.x); split_bf16(v.y, h4.y, l4.y);
        split_bf16(v.z, h4.z, l4.z); split_bf16(v.w, h4.w, l4.w);
        *reinterpret_cast<short4*>(&hbuf[row][c4]) = h4;
        *reinterpret_cast<short4*>(&lbuf[row][c4]) = l4;
    }
    __syncthreads();
    #pragma unroll
    for (int f = 0; f < 16; ++f) {
        int u = t + f * 256;                  // 16B units: lane fastest
        int lane = u & 63, h = (u >> 6) & 1, kb = u >> 7;
        int row = lane & 31, k0 = kb * 16 + (lane >> 5) * 8;
        const short* s = h ? &lbuf[row][k0] : &hbuf[row][k0];
        short8v val = *reinterpret_cast<const short8v*>(s);
        *reinterpret_cast<short8v*>(&dst[(size_t)u * 8]) = val;
    }
}

// ---------------- argmin: LDS-free fragment-direct MFMA GEMM ----------------
// 128x128 tile, 4 waves (2x2), wave = 2x2 mfma 32x32x16, 3 split products.
// All operands loaded as ready-made fragments (coalesced 16B/lane); wave
// duplication served by L1/L2. XCD-chunked bid keeps row-tile + E in L2.
__global__ __launch_bounds__(256, 3) void k_argmin(const short* __restrict__ xfrag,
                                                   const short* __restrict__ efrag,
                                                   const float* __restrict__ en2,
                                                   unsigned long long* __restrict__ packed) {
    const int tid = threadIdx.x;
    const int w = tid >> 6, l = tid & 63;
    const int wr = w >> 1, wc = w & 1;
    const int l31 = l & 31, lh = l >> 5;

    int bid = blockIdx.x;                // 2048 blocks
    int xcd = bid & 7, j = bid >> 3;
    int row0 = (xcd * 32 + (j >> 3)) * 128;
    int c0   = (j & 7) * 128;

    const short* ab[2];
    const short* bb[2];
    #pragma unroll
    for (int tm = 0; tm < 2; ++tm)
        ab[tm] = xfrag + (size_t)(row0 / 32 + wr * 2 + tm) * 32768 + l * 8;
    #pragma unroll
    for (int tn = 0; tn < 2; ++tn)
        bb[tn] = efrag + (size_t)(c0 / 32 + wc * 2 + tn) * 32768 + l * 8;

    f32x16 acc[2][2];
    #pragma unroll
    for (int a = 0; a < 2; ++a)
        #pragma unroll
        for (int b = 0; b < 2; ++b)
            #pragma unroll
            for (int r = 0; r < 16; ++r) acc[a][b][r] = 0.f;

    #pragma unroll 2
    for (int kb = 0; kb < 32; ++kb) {
        short8v axh[2], axl[2], beh[2], bel[2];
        #pragma unroll
        for (int tm = 0; tm < 2; ++tm) {
            axh[tm] = *reinterpret_cast<const short8v*>(ab[tm] + kb * 1024);
            axl[tm] = *reinterpret_cast<const short8v*>(ab[tm] + kb * 1024 + 512);
        }
        #pragma unroll
        for (int tn = 0; tn < 2; ++tn) {
            beh[tn] = *reinterpret_cast<const short8v*>(bb[tn] + kb * 1024);
            bel[tn] = *reinterpret_cast<const short8v*>(bb[tn] + kb * 1024 + 512);
        }
        #pragma unroll
        for (int tm = 0; tm < 2; ++tm)
            #pragma unroll
            for (int tn = 0; tn < 2; ++tn) {
                acc[tm][tn] = __builtin_amdgcn_mfma_f32_32x32x16_bf16(
                    axh[tm], beh[tn], acc[tm][tn], 0, 0, 0);
                acc[tm][tn] = __builtin_amdgcn_mfma_f32_32x32x16_bf16(
                    axh[tm], bel[tn], acc[tm][tn], 0, 0, 0);
                acc[tm][tn] = __builtin_amdgcn_mfma_f32_32x32x16_bf16(
                    axl[tm], beh[tn], acc[tm][tn], 0, 0, 0);
            }
    }

    // epilogue: dist = ||e||^2 - 2 x.e ; D layout: col=l&31,
    // row=(r&3)+8*(r>>2)+4*(l>>5)
    float e2[2];
    #pragma unroll
    for (int tn = 0; tn < 2; ++tn) e2[tn] = en2[c0 + wc * 64 + tn * 32 + l31];
    const int cA = c0 + wc * 64 + l31;
    #pragma unroll
    for (int tm = 0; tm < 2; ++tm) {
        #pragma unroll
        for (int r = 0; r < 16; ++r) {
            float d0 = fmaf(-2.f, acc[tm][0][r], e2[0]);
            float d1 = fmaf(-2.f, acc[tm][1][r], e2[1]);
            unsigned long long k0 = pack_key(d0, cA);
            unsigned long long k1 = pack_key(d1, cA + 32);
            unsigned long long key = k0 < k1 ? k0 : k1;
            #pragma unroll
            for (int off = 1; off < 32; off <<= 1) {
                unsigned long long o = __shfl_xor(key, off);
                if (o < key) key = o;
            }
            if (l31 == 0) {
                int grow = row0 + wr * 64 + tm * 32 + (r & 3) + 8 * (r >> 2) + 4 * lh;
                atomicMin(&packed[grow], key);
            }
        }
    }
}

// ---------------- unpack idx + histogram ----------------
__global__ __launch_bounds__(256) void k_hist(const unsigned long long* __restrict__ packed,
                                              int* __restrict__ idx,
                                              int* __restrict__ counts) {
    __shared__ int h[KC];
    for (int i = threadIdx.x; i < KC; i += 256) h[i] = 0;
    __syncthreads();
    int g = blockIdx.x * 256 + threadIdx.x;
    int c = (int)(unsigned)(packed[g] & 0xFFFFFFFFull);
    idx[g] = c;
    atomicAdd(&h[c], 1);
    __syncthreads();
    for (int i = threadIdx.x; i < KC; i += 256)
        if (h[i]) atomicAdd(&counts[i], h[i]);
}

// ---------------- smoothing, perplexity, prefix sums ----------------
__global__ __launch_bounds__(1024) void k_meta(const int* __restrict__ counts,
                                               const float* __restrict__ ema_cs,
                                               float* __restrict__ smoothed,
                                               int* __restrict__ offsets,
                                               int* __restrict__ cursor,
                                               float* __restrict__ perp_out) {
    __shared__ float red[KC];
    __shared__ int sc[KC];
    int t = threadIdx.x;
    int cnt = counts[t];
    float cs = ema_cs[t] * 0.99f + 0.01f * (float)cnt;
    red[t] = cs; __syncthreads();
    for (int s = 512; s; s >>= 1) { if (t < s) red[t] += red[t + s]; __syncthreads(); }
    float n = red[0];
    __syncthreads();
    float sm = (cs + 1e-5f) / (n + 1024.f * 1e-5f) * n;
    smoothed[t] = sm;
    float p = (float)cnt / 32768.f;
    red[t] = p * logf(p + 1e-10f);
    __syncthreads();
    for (int s = 512; s; s >>= 1) { if (t < s) red[t] += red[t + s]; __syncthreads(); }
    if (!t) perp_out[0] = expf(-red[0]);
    sc[t] = cnt; __syncthreads();
    for (int s = 1; s < KC; s <<= 1) {
        int v = (t >= s) ? sc[t - s] : 0;
        __syncthreads();
        sc[t] += v;
        __syncthreads();
    }
    int off = sc[t] - cnt;
    offsets[t] = off;
    cursor[t] = off;
}

// ---------------- CSR bucket scatter ----------------
__global__ __launch_bounds__(256) void k_scatter(const int* __restrict__ idx,
                                                 int* __restrict__ cursor,
                                                 int* __restrict__ bucket) {
    int g = blockIdx.x * 256 + threadIdx.x;
    int c = idx[g];
    int pos = atomicAdd(&cursor[c], 1);
    bucket[pos] = g;
}

// ---------------- one-hot encodings: full-row writer ----------------
__global__ __launch_bounds__(256) void k_enc(const int* __restrict__ idx,
                                             float* __restrict__ enc) {
    int t = threadIdx.x;
    int row = blockIdx.x * 8 + (t >> 5);
    int l32 = t & 31;
    int one = idx[row];
    float4* dst = reinterpret_cast<float4*>(enc + (size_t)row * KC);
    #pragma unroll
    for (int s = 0; s < 8; ++s) {
        int c4 = l32 + s * 32;
        int base = c4 * 4;
        float4 v;
        v.x = (one == base)     ? 1.f : 0.f;
        v.y = (one == base + 1) ? 1.f : 0.f;
        v.z = (one == base + 2) ? 1.f : 0.f;
        v.w = (one == base + 3) ? 1.f : 0.f;
        dst[c4] = v;
    }
}

// ---------------- segment-sum + new embedding (LDS-staged, unrolled) ------
__global__ __launch_bounds__(256) void k_dw(const float* __restrict__ x,
                                            const float* __restrict__ ema_w,
                                            const int* __restrict__ offsets,
                                            const int* __restrict__ counts,
                                            const int* __restrict__ bucket,
                                            const float* __restrict__ smoothed,
                                            float* __restrict__ newE) {
    __shared__ int rows[256];
    int k = blockIdx.x, t = threadIdx.x;
    int beg = offsets[k], m = counts[k];
    float a0 = 0.f, a1 = 0.f;
    for (int base = 0; base < m; base += 256) {
        int n = min(256, m - base);
        __syncthreads();
        if (t < n) rows[t] = bucket[beg + base + t];
        __syncthreads();
        int i = 0;
        for (; i + 4 <= n; i += 4) {
            int r0 = rows[i], r1 = rows[i + 1], r2 = rows[i + 2], r3 = rows[i + 3];
            float v00 = x[(size_t)r0 * DIM + t];
            float v01 = x[(size_t)r0 * DIM + t + 256];
            float v10 = x[(size_t)r1 * DIM + t];
            float v11 = x[(size_t)r1 * DIM + t + 256];
            float v20 = x[(size_t)r2 * DIM + t];
            float v21 = x[(size_t)r2 * DIM + t + 256];
            float v30 = x[(size_t)r3 * DIM + t];
            float v31 = x[(size_t)r3 * DIM + t + 256];
            a0 += v00 + v10 + v20 + v30;
            a1 += v01 + v11 + v21 + v31;
        }
        for (; i < n; ++i) {
            int r = rows[i];
            a0 += x[(size_t)r * DIM + t];
            a1 += x[(size_t)r * DIM + t + 256];
        }
    }
    float sm = smoothed[k];
    newE[(size_t)k * DIM + t]       = (ema_w[(size_t)k * DIM + t]       * 0.99f + 0.01f * a0) / sm;
    newE[(size_t)k * DIM + t + 256] = (ema_w[(size_t)k * DIM + t + 256] * 0.99f + 0.01f * a1) / sm;
}

// ---------------- quantized output (STE) + loss partials ----------------
__global__ __launch_bounds__(256) void k_quant(const float* __restrict__ x,
                                               const int* __restrict__ idx,
                                               const float* __restrict__ newE,
                                               float* __restrict__ outq,
                                               float* __restrict__ partials) {
    int t0 = blockIdx.x * 256 + threadIdx.x;
    float lp = 0.f;
    #pragma unroll 4
    for (int s = 0; s < 16; ++s) {
        int e = t0 + s * 1048576;
        int row = e >> 9;
        int c = idx[row];
        float in = x[e];
        float q = newE[(size_t)c * DIM + (e & 511)];
        float d = q - in;
        outq[e] = in + d;
        lp += d * d;
    }
    #pragma unroll
    for (int off = 32; off; off >>= 1) lp += __shfl_xor(lp, off);
    __shared__ float wr[4];
    int lane = threadIdx.x & 63, w = threadIdx.x >> 6;
    if (!lane) wr[w] = lp;
    __syncthreads();
    if (threadIdx.x == 0) partials[blockIdx.x] = wr[0] + wr[1] + wr[2] + wr[3];
}

__global__ __launch_bounds__(256) void k_lossfin(const float* __restrict__ partials,
                                                 float* __restrict__ out0) {
    __shared__ double red[256];
    double s = 0.0;
    for (int i = threadIdx.x; i < 4096; i += 256) s += (double)partials[i];
    red[threadIdx.x] = s; __syncthreads();
    for (int st = 128; st; st >>= 1) {
        if (threadIdx.x < st) red[threadIdx.x] += red[threadIdx.x + st];
        __syncthreads();
    }
    if (!threadIdx.x) out0[0] = (float)(0.25 * red[0] / 16777216.0);
}

extern "C" void kernel_launch(void* const* d_in, const int* in_sizes, int n_in,
                              void* d_out, int out_size, void* d_ws, size_t ws_size,
                              hipStream_t stream) {
    const float* x   = (const float*)d_in[0];
    const float* E   = (const float*)d_in[1];
    const float* ecs = (const float*)d_in[2];
    const float* emw = (const float*)d_in[3];
    float* out = (float*)d_out;

    char* ws = (char*)d_ws;
    int*   idx      = (int*)(ws + 0);                  // 128 KB
    int*   bucket   = (int*)(ws + 131072);             // 128 KB
    float* en2      = (float*)(ws + 262144);           // 4 KB
    int*   counts   = (int*)(ws + 266240);             // 4 KB
    int*   offsets  = (int*)(ws + 270336);             // 4 KB
    int*   cursor   = (int*)(ws + 274432);             // 4 KB
    float* smoothed = (float*)(ws + 278528);           // 4 KB
    float* newE     = (float*)(ws + 282624);           // 2 MB
    float* partials = (float*)(ws + 282624 + 2097152); // 16 KB
    unsigned long long* packed = (unsigned long long*)newE;  // dead before k_dw

    float* out_loss = out;
    float* out_q    = out + 1;
    float* out_perp = out + 16777217;
    float* out_enc  = out + 16777218;

    // fragment scratch lives in out_enc (128 MB, rewritten by k_enc later):
    // xfrag 64 MB + efrag 2 MB
    short* xfrag = (short*)out_enc;
    short* efrag = xfrag + (size_t)NROWS * DIM * 2;

    hipMemsetAsync(counts, 0, KC * sizeof(int), stream);
    hipMemsetAsync(packed, 0xFF, NROWS * sizeof(unsigned long long), stream);

    k_enorm  <<<KC / 4, 256, 0, stream>>>(E, en2);
    k_split  <<<NROWS / 32 + KC / 32, 256, 0, stream>>>(x, E, xfrag, efrag);
    k_argmin <<<(NROWS / 128) * 8, 256, 0, stream>>>(xfrag, efrag, en2, packed);
    k_hist   <<<NROWS / 256, 256, 0, stream>>>(packed, idx, counts);
    k_meta   <<<1, 1024, 0, stream>>>(counts, ecs, smoothed, offsets, cursor, out_perp);
    k_scatter<<<NROWS / 256, 256, 0, stream>>>(idx, cursor, bucket);
    k_enc    <<<NROWS / 8, 256, 0, stream>>>(idx, out_enc);
    k_dw     <<<KC, 256, 0, stream>>>(x, emw, offsets, counts, bucket, smoothed, newE);
    k_quant  <<<4096, 256, 0, stream>>>(x, idx, newE, out_q, partials);
    k_lossfin<<<1, 256, 0, stream>>>(partials, out_loss);
}

// Round 6
// 314.729 us; speedup vs baseline: 2.9239x; 1.0826x over previous
//
#include <hip/hip_runtime.h>

#define NROWS 32768
#define DIM   512
#define KC    1024

typedef __attribute__((ext_vector_type(8)))  short short8v;
typedef __attribute__((ext_vector_type(16))) float f32x16;

// ---------------- e_norm2: ||E[k]||^2 (exact fp32) ----------------
__global__ __launch_bounds__(256) void k_enorm(const float* __restrict__ E,
                                               float* __restrict__ en2) {
    int w = threadIdx.x >> 6, lane = threadIdx.x & 63;
    int c = blockIdx.x * 4 + w;
    const float* row = E + (size_t)c * DIM;
    float4 a = *reinterpret_cast<const float4*>(&row[lane * 8]);
    float4 b = *reinterpret_cast<const float4*>(&row[lane * 8 + 4]);
    float s = a.x*a.x + a.y*a.y + a.z*a.z + a.w*a.w
            + b.x*b.x + b.y*b.y + b.z*b.z + b.w*b.w;
    #pragma unroll
    for (int off = 32; off; off >>= 1) s += __shfl_xor(s, off);
    if (!lane) en2[c] = s;
}

// RTN float -> bf16(short), plus residual bf16
__device__ __forceinline__ void split_bf16(float v, short& hi, short& lo) {
    unsigned u = __float_as_uint(v);
    unsigned r = u + 0x7FFFu + ((u >> 16) & 1u);
    hi = (short)(r >> 16);
    float hif = __uint_as_float(r & 0xFFFF0000u);
    float rem = v - hif;
    unsigned u2 = __float_as_uint(rem);
    unsigned r2 = u2 + 0x7FFFu + ((u2 >> 16) & 1u);
    lo = (short)(r2 >> 16);
}

__device__ __forceinline__ unsigned long long pack_key(float d, int c) {
    unsigned u = __float_as_uint(d);
    u = (u & 0x80000000u) ? ~u : (u | 0x80000000u);   // monotone for min
    return ((unsigned long long)u << 32) | (unsigned)c;
}

// ---------------- split x and E to bf16 hi/lo in MFMA fragment layout -----
// per 32-row group: [kb 0..31][h 0..1][lane 0..63][8 shorts]
// fragment: lane l holds rows l&31, k = kb*16 + (l>>5)*8 .. +7
__global__ __launch_bounds__(256) void k_split(const float* __restrict__ x,
                                               const float* __restrict__ E,
                                               short* __restrict__ xfrag,
                                               short* __restrict__ efrag) {
    __shared__ short hbuf[32][520];
    __shared__ short lbuf[32][520];
    int b = blockIdx.x, t = threadIdx.x;
    const float* src;
    short* dst;
    if (b < NROWS / 32) {
        src = x + (size_t)b * 32 * DIM;
        dst = xfrag + (size_t)b * 32768;
    } else {
        src = E + (size_t)(b - NROWS / 32) * 32 * DIM;
        dst = efrag + (size_t)(b - NROWS / 32) * 32768;
    }
    #pragma unroll
    for (int f = 0; f < 16; ++f) {
        int u = t + f * 256;
        int row = u >> 7, c4 = (u & 127) * 4;
        float4 v = *reinterpret_cast<const float4*>(&src[row * DIM + c4]);
        short4 h4, l4;
        split_bf16(v.x, h4.x, l4.x); split_bf16(v.y, h4.y, l4.y);
        split_bf16(v.z, h4.z, l4.z); split_bf16(v.w, h4.w, l4.w);
        *reinterpret_cast<short4*>(&hbuf[row][c4]) = h4;
        *reinterpret_cast<short4*>(&lbuf[row][c4]) = l4;
    }
    __syncthreads();
    #pragma unroll
    for (int f = 0; f < 16; ++f) {
        int u = t + f * 256;
        int lane = u & 63, h = (u >> 6) & 1, kb = u >> 7;
        int row = lane & 31, k0 = kb * 16 + (lane >> 5) * 8;
        const short* s = h ? &lbuf[row][k0] : &hbuf[row][k0];
        short8v val = *reinterpret_cast<const short8v*>(s);
        *reinterpret_cast<short8v*>(&dst[(size_t)u * 8]) = val;
    }
}

// ---------------- argmin: LDS-staged fragment MFMA GEMM -------------------
// block tile 128 rows x 256 codes, 4 waves each 64x128 (2m x 4n mfma 32x32).
// per K-step: stage 24 chunks of 1KB (4 x-groups + 8 e-groups, hi+lo) into
// LDS once (reg-staged, double-buffered, loads issued before MFMA section),
// waves ds_read_b128 fragments. grid 1024 = 256 row-tiles x 4 code-splits,
// XCD-chunked. cross-split argmin via packed atomicMin.
__global__ __launch_bounds__(256, 2) void k_argmin(const short* __restrict__ xfrag,
                                                   const short* __restrict__ efrag,
                                                   const float* __restrict__ en2,
                                                   unsigned long long* __restrict__ packed) {
    __shared__ short sbuf[2][24 * 512];   // 48 KB
    const int tid = threadIdx.x;
    const int w = tid >> 6, l = tid & 63;
    const int wr = w >> 1, wc = w & 1;
    const int l31 = l & 31, lh = l >> 5;

    int bid = blockIdx.x;                 // 1024 blocks
    int xcd = bid & 7, j = bid >> 3;      // j 0..127
    int row0 = (xcd * 32 + (j >> 2)) * 128;
    int c0   = (j & 3) * 256;

    // staging source bases: thread t stages chunks q = s*4 + (t>>6), s=0..5
    const short* srcbase[6];
    #pragma unroll
    for (int s = 0; s < 6; ++s) {
        int q = s * 4 + (tid >> 6);
        int g = q >> 1, h = q & 1;
        const short* base = (g < 4)
            ? xfrag + (size_t)(row0 / 32 + g) * 32768
            : efrag + (size_t)(c0 / 32 + (g - 4)) * 32768;
        srcbase[s] = base + h * 512 + (tid & 63) * 8;
    }
    const int stq = tid >> 6;             // chunk group offset
    const int stl = (tid & 63) * 8;

    f32x16 acc[2][4];
    #pragma unroll
    for (int a = 0; a < 2; ++a)
        #pragma unroll
        for (int b = 0; b < 4; ++b)
            #pragma unroll
            for (int r = 0; r < 16; ++r) acc[a][b][r] = 0.f;

    // prologue: stage kb=0 into buf 0
    {
        short8v st[6];
        #pragma unroll
        for (int s = 0; s < 6; ++s)
            st[s] = *reinterpret_cast<const short8v*>(srcbase[s]);
        #pragma unroll
        for (int s = 0; s < 6; ++s)
            *reinterpret_cast<short8v*>(&sbuf[0][(s * 4 + stq) * 512 + stl]) = st[s];
    }
    __syncthreads();

    for (int kb = 0; kb < 32; ++kb) {
        const int cur = kb & 1;
        short8v st[6];
        if (kb < 31) {
            #pragma unroll
            for (int s = 0; s < 6; ++s)
                st[s] = *reinterpret_cast<const short8v*>(
                    srcbase[s] + (size_t)(kb + 1) * 1024);
        }
        // fragment reads: A (2 m-groups x hi/lo), B (4 n-groups x hi/lo)
        short8v ah[2], al[2], bh[4], bl[4];
        const short* sb = sbuf[cur];
        #pragma unroll
        for (int m = 0; m < 2; ++m) {
            int g = wr * 2 + m;
            ah[m] = *reinterpret_cast<const short8v*>(&sb[(g * 2 + 0) * 512 + l * 8]);
            al[m] = *reinterpret_cast<const short8v*>(&sb[(g * 2 + 1) * 512 + l * 8]);
        }
        #pragma unroll
        for (int n = 0; n < 4; ++n) {
            int g = 4 + wc * 4 + n;
            bh[n] = *reinterpret_cast<const short8v*>(&sb[(g * 2 + 0) * 512 + l * 8]);
            bl[n] = *reinterpret_cast<const short8v*>(&sb[(g * 2 + 1) * 512 + l * 8]);
        }
        #pragma unroll
        for (int m = 0; m < 2; ++m)
            #pragma unroll
            for (int n = 0; n < 4; ++n) {
                acc[m][n] = __builtin_amdgcn_mfma_f32_32x32x16_bf16(
                    ah[m], bh[n], acc[m][n], 0, 0, 0);
                acc[m][n] = __builtin_amdgcn_mfma_f32_32x32x16_bf16(
                    ah[m], bl[n], acc[m][n], 0, 0, 0);
                acc[m][n] = __builtin_amdgcn_mfma_f32_32x32x16_bf16(
                    al[m], bh[n], acc[m][n], 0, 0, 0);
            }
        if (kb < 31) {
            #pragma unroll
            for (int s = 0; s < 6; ++s)
                *reinterpret_cast<short8v*>(
                    &sbuf[cur ^ 1][(s * 4 + stq) * 512 + stl]) = st[s];
        }
        __syncthreads();
    }

    // epilogue: dist = ||e||^2 - 2 x.e ; D layout: col=l&31,
    // row=(r&3)+8*(r>>2)+4*(l>>5)
    float e2[4];
    #pragma unroll
    for (int n = 0; n < 4; ++n) e2[n] = en2[c0 + wc * 128 + n * 32 + l31];
    #pragma unroll
    for (int m = 0; m < 2; ++m) {
        #pragma unroll
        for (int r = 0; r < 16; ++r) {
            unsigned long long key = 0xFFFFFFFFFFFFFFFFull;
            #pragma unroll
            for (int n = 0; n < 4; ++n) {
                float d = fmaf(-2.f, acc[m][n][r], e2[n]);
                unsigned long long k = pack_key(d, c0 + wc * 128 + n * 32 + l31);
                if (k < key) key = k;
            }
            #pragma unroll
            for (int off = 1; off < 32; off <<= 1) {
                unsigned long long o = __shfl_xor(key, off);
                if (o < key) key = o;
            }
            if (l31 == 0) {
                int grow = row0 + wr * 64 + m * 32 + (r & 3) + 8 * (r >> 2) + 4 * lh;
                atomicMin(&packed[grow], key);
            }
        }
    }
}

// ---------------- unpack idx + histogram ----------------
__global__ __launch_bounds__(256) void k_hist(const unsigned long long* __restrict__ packed,
                                              int* __restrict__ idx,
                                              int* __restrict__ counts) {
    __shared__ int h[KC];
    for (int i = threadIdx.x; i < KC; i += 256) h[i] = 0;
    __syncthreads();
    int g = blockIdx.x * 256 + threadIdx.x;
    int c = (int)(unsigned)(packed[g] & 0xFFFFFFFFull);
    idx[g] = c;
    atomicAdd(&h[c], 1);
    __syncthreads();
    for (int i = threadIdx.x; i < KC; i += 256)
        if (h[i]) atomicAdd(&counts[i], h[i]);
}

// ---------------- smoothing, perplexity, prefix sums ----------------
__global__ __launch_bounds__(1024) void k_meta(const int* __restrict__ counts,
                                               const float* __restrict__ ema_cs,
                                               float* __restrict__ smoothed,
                                               int* __restrict__ offsets,
                                               int* __restrict__ cursor,
                                               float* __restrict__ perp_out) {
    __shared__ float red[KC];
    __shared__ int sc[KC];
    int t = threadIdx.x;
    int cnt = counts[t];
    float cs = ema_cs[t] * 0.99f + 0.01f * (float)cnt;
    red[t] = cs; __syncthreads();
    for (int s = 512; s; s >>= 1) { if (t < s) red[t] += red[t + s]; __syncthreads(); }
    float n = red[0];
    __syncthreads();
    float sm = (cs + 1e-5f) / (n + 1024.f * 1e-5f) * n;
    smoothed[t] = sm;
    float p = (float)cnt / 32768.f;
    red[t] = p * logf(p + 1e-10f);
    __syncthreads();
    for (int s = 512; s; s >>= 1) { if (t < s) red[t] += red[t + s]; __syncthreads(); }
    if (!t) perp_out[0] = expf(-red[0]);
    sc[t] = cnt; __syncthreads();
    for (int s = 1; s < KC; s <<= 1) {
        int v = (t >= s) ? sc[t - s] : 0;
        __syncthreads();
        sc[t] += v;
        __syncthreads();
    }
    int off = sc[t] - cnt;
    offsets[t] = off;
    cursor[t] = off;
}

// ---------------- CSR bucket scatter ----------------
__global__ __launch_bounds__(256) void k_scatter(const int* __restrict__ idx,
                                                 int* __restrict__ cursor,
                                                 int* __restrict__ bucket) {
    int g = blockIdx.x * 256 + threadIdx.x;
    int c = idx[g];
    int pos = atomicAdd(&cursor[c], 1);
    bucket[pos] = g;
}

// ---------------- segment-sum + new embedding (LDS-staged, unrolled) ------
__global__ __launch_bounds__(256) void k_dw(const float* __restrict__ x,
                                            const float* __restrict__ ema_w,
                                            const int* __restrict__ offsets,
                                            const int* __restrict__ counts,
                                            const int* __restrict__ bucket,
                                            const float* __restrict__ smoothed,
                                            float* __restrict__ newE) {
    __shared__ int rows[256];
    int k = blockIdx.x, t = threadIdx.x;
    int beg = offsets[k], m = counts[k];
    float a0 = 0.f, a1 = 0.f;
    for (int base = 0; base < m; base += 256) {
        int n = min(256, m - base);
        __syncthreads();
        if (t < n) rows[t] = bucket[beg + base + t];
        __syncthreads();
        int i = 0;
        for (; i + 4 <= n; i += 4) {
            int r0 = rows[i], r1 = rows[i + 1], r2 = rows[i + 2], r3 = rows[i + 3];
            float v00 = x[(size_t)r0 * DIM + t];
            float v01 = x[(size_t)r0 * DIM + t + 256];
            float v10 = x[(size_t)r1 * DIM + t];
            float v11 = x[(size_t)r1 * DIM + t + 256];
            float v20 = x[(size_t)r2 * DIM + t];
            float v21 = x[(size_t)r2 * DIM + t + 256];
            float v30 = x[(size_t)r3 * DIM + t];
            float v31 = x[(size_t)r3 * DIM + t + 256];
            a0 += v00 + v10 + v20 + v30;
            a1 += v01 + v11 + v21 + v31;
        }
        for (; i < n; ++i) {
            int r = rows[i];
            a0 += x[(size_t)r * DIM + t];
            a1 += x[(size_t)r * DIM + t + 256];
        }
    }
    float sm = smoothed[k];
    newE[(size_t)k * DIM + t]       = (ema_w[(size_t)k * DIM + t]       * 0.99f + 0.01f * a0) / sm;
    newE[(size_t)k * DIM + t + 256] = (ema_w[(size_t)k * DIM + t + 256] * 0.99f + 0.01f * a1) / sm;
}

// ---------------- fused quantized (STE) + one-hot + loss partials ---------
// block handles 8 rows: quant 8x512 floats + enc 8x1024 floats
__global__ __launch_bounds__(256) void k_qe(const float* __restrict__ x,
                                            const int* __restrict__ idx,
                                            const float* __restrict__ newE,
                                            float* __restrict__ outq,
                                            float* __restrict__ enc,
                                            float* __restrict__ partials) {
    int b = blockIdx.x, t = threadIdx.x;
    int row8 = b * 8;
    float lp = 0.f;
    #pragma unroll
    for (int it = 0; it < 4; ++it) {
        int slot = t + it * 256;            // 0..1023 float4 slots over 8x512
        int r = slot >> 7;
        int c4 = (slot & 127) * 4;
        int row = row8 + r;
        int code = idx[row];
        float4 in = *reinterpret_cast<const float4*>(&x[(size_t)row * DIM + c4]);
        float4 q  = *reinterpret_cast<const float4*>(&newE[(size_t)code * DIM + c4]);
        float4 d;
        d.x = q.x - in.x; d.y = q.y - in.y; d.z = q.z - in.z; d.w = q.w - in.w;
        float4 o;
        o.x = in.x + d.x; o.y = in.y + d.y; o.z = in.z + d.z; o.w = in.w + d.w;
        *reinterpret_cast<float4*>(&outq[(size_t)row * DIM + c4]) = o;
        lp += d.x*d.x + d.y*d.y + d.z*d.z + d.w*d.w;
    }
    // one-hot rows: 8 rows x 32 lanes, 8 float4 each
    {
        int er = row8 + (t >> 5);
        int l32 = t & 31;
        int one = idx[er];
        float4* dst = reinterpret_cast<float4*>(enc + (size_t)er * KC);
        #pragma unroll
        for (int s = 0; s < 8; ++s) {
            int c4 = l32 + s * 32;
            int base = c4 * 4;
            float4 v;
            v.x = (one == base)     ? 1.f : 0.f;
            v.y = (one == base + 1) ? 1.f : 0.f;
            v.z = (one == base + 2) ? 1.f : 0.f;
            v.w = (one == base + 3) ? 1.f : 0.f;
            dst[c4] = v;
        }
    }
    #pragma unroll
    for (int off = 32; off; off >>= 1) lp += __shfl_xor(lp, off);
    __shared__ float wr[4];
    int lane = t & 63, w = t >> 6;
    if (!lane) wr[w] = lp;
    __syncthreads();
    if (t == 0) partials[b] = wr[0] + wr[1] + wr[2] + wr[3];
}

__global__ __launch_bounds__(256) void k_lossfin(const float* __restrict__ partials,
                                                 float* __restrict__ out0) {
    __shared__ double red[256];
    double s = 0.0;
    for (int i = threadIdx.x; i < 4096; i += 256) s += (double)partials[i];
    red[threadIdx.x] = s; __syncthreads();
    for (int st = 128; st; st >>= 1) {
        if (threadIdx.x < st) red[threadIdx.x] += red[threadIdx.x + st];
        __syncthreads();
    }
    if (!threadIdx.x) out0[0] = (float)(0.25 * red[0] / 16777216.0);
}

extern "C" void kernel_launch(void* const* d_in, const int* in_sizes, int n_in,
                              void* d_out, int out_size, void* d_ws, size_t ws_size,
                              hipStream_t stream) {
    const float* x   = (const float*)d_in[0];
    const float* E   = (const float*)d_in[1];
    const float* ecs = (const float*)d_in[2];
    const float* emw = (const float*)d_in[3];
    float* out = (float*)d_out;

    char* ws = (char*)d_ws;
    int*   idx      = (int*)(ws + 0);                  // 128 KB
    int*   bucket   = (int*)(ws + 131072);             // 128 KB
    float* en2      = (float*)(ws + 262144);           // 4 KB
    int*   counts   = (int*)(ws + 266240);             // 4 KB
    int*   offsets  = (int*)(ws + 270336);             // 4 KB
    int*   cursor   = (int*)(ws + 274432);             // 4 KB
    float* smoothed = (float*)(ws + 278528);           // 4 KB
    float* newE     = (float*)(ws + 282624);           // 2 MB
    float* partials = (float*)(ws + 282624 + 2097152); // 16 KB
    unsigned long long* packed = (unsigned long long*)newE;  // dead before k_dw

    float* out_loss = out;
    float* out_q    = out + 1;
    float* out_perp = out + 16777217;
    float* out_enc  = out + 16777218;

    // fragment scratch lives in out_enc (128 MB, rewritten by k_qe later):
    // xfrag 64 MB + efrag 2 MB
    short* xfrag = (short*)out_enc;
    short* efrag = xfrag + (size_t)NROWS * DIM * 2;

    hipMemsetAsync(counts, 0, KC * sizeof(int), stream);
    hipMemsetAsync(packed, 0xFF, NROWS * sizeof(unsigned long long), stream);

    k_enorm  <<<KC / 4, 256, 0, stream>>>(E, en2);
    k_split  <<<NROWS / 32 + KC / 32, 256, 0, stream>>>(x, E, xfrag, efrag);
    k_argmin <<<(NROWS / 128) * 4, 256, 0, stream>>>(xfrag, efrag, en2, packed);
    k_hist   <<<NROWS / 256, 256, 0, stream>>>(packed, idx, counts);
    k_meta   <<<1, 1024, 0, stream>>>(counts, ecs, smoothed, offsets, cursor, out_perp);
    k_scatter<<<NROWS / 256, 256, 0, stream>>>(idx, cursor, bucket);
    k_dw     <<<KC, 256, 0, stream>>>(x, emw, offsets, counts, bucket, smoothed, newE);
    k_qe     <<<NROWS / 8, 256, 0, stream>>>(x, idx, newE, out_q, out_enc, partials);
    k_lossfin<<<1, 256, 0, stream>>>(partials, out_loss);
}

// Round 7
// 310.039 us; speedup vs baseline: 2.9682x; 1.0151x over previous
//
#include <hip/hip_runtime.h>

#define NROWS 32768
#define DIM   512
#define KC    1024

typedef __attribute__((ext_vector_type(8)))  short short8v;
typedef __attribute__((ext_vector_type(16))) float f32x16;

#define AS1 __attribute__((address_space(1)))
#define AS3 __attribute__((address_space(3)))

// ---------------- e_norm2: ||E[k]||^2 (exact fp32) ----------------
__global__ __launch_bounds__(256) void k_enorm(const float* __restrict__ E,
                                               float* __restrict__ en2) {
    int w = threadIdx.x >> 6, lane = threadIdx.x & 63;
    int c = blockIdx.x * 4 + w;
    const float* row = E + (size_t)c * DIM;
    float4 a = *reinterpret_cast<const float4*>(&row[lane * 8]);
    float4 b = *reinterpret_cast<const float4*>(&row[lane * 8 + 4]);
    float s = a.x*a.x + a.y*a.y + a.z*a.z + a.w*a.w
            + b.x*b.x + b.y*b.y + b.z*b.z + b.w*b.w;
    #pragma unroll
    for (int off = 32; off; off >>= 1) s += __shfl_xor(s, off);
    if (!lane) en2[c] = s;
}

// RTN float -> bf16(short), plus residual bf16
__device__ __forceinline__ void split_bf16(float v, short& hi, short& lo) {
    unsigned u = __float_as_uint(v);
    unsigned r = u + 0x7FFFu + ((u >> 16) & 1u);
    hi = (short)(r >> 16);
    float hif = __uint_as_float(r & 0xFFFF0000u);
    float rem = v - hif;
    unsigned u2 = __float_as_uint(rem);
    unsigned r2 = u2 + 0x7FFFu + ((u2 >> 16) & 1u);
    lo = (short)(r2 >> 16);
}

__device__ __forceinline__ unsigned long long pack_key(float d, int c) {
    unsigned u = __float_as_uint(d);
    u = (u & 0x80000000u) ? ~u : (u | 0x80000000u);   // monotone for min
    return ((unsigned long long)u << 32) | (unsigned)c;
}

// ---------------- split x and E to bf16 hi/lo in MFMA fragment layout -----
// per 32-row group: [kb 0..31][h 0..1][lane 0..63][8 shorts]
// fragment: lane l holds rows l&31, k = kb*16 + (l>>5)*8 .. +7
__global__ __launch_bounds__(256) void k_split(const float* __restrict__ x,
                                               const float* __restrict__ E,
                                               short* __restrict__ xfrag,
                                               short* __restrict__ efrag) {
    __shared__ short hbuf[32][520];
    __shared__ short lbuf[32][520];
    int b = blockIdx.x, t = threadIdx.x;
    const float* src;
    short* dst;
    if (b < NROWS / 32) {
        src = x + (size_t)b * 32 * DIM;
        dst = xfrag + (size_t)b * 32768;
    } else {
        src = E + (size_t)(b - NROWS / 32) * 32 * DIM;
        dst = efrag + (size_t)(b - NROWS / 32) * 32768;
    }
    #pragma unroll
    for (int f = 0; f < 16; ++f) {
        int u = t + f * 256;
        int row = u >> 7, c4 = (u & 127) * 4;
        float4 v = *reinterpret_cast<const float4*>(&src[row * DIM + c4]);
        short4 h4, l4;
        split_bf16(v.x, h4.x, l4.x); split_bf16(v.y, h4.y, l4.y);
        split_bf16(v.z, h4.z, l4.z); split_bf16(v.w, h4.w, l4.w);
        *reinterpret_cast<short4*>(&hbuf[row][c4]) = h4;
        *reinterpret_cast<short4*>(&lbuf[row][c4]) = l4;
    }
    __syncthreads();
    #pragma unroll
    for (int f = 0; f < 16; ++f) {
        int u = t + f * 256;
        int lane = u & 63, h = (u >> 6) & 1, kb = u >> 7;
        int row = lane & 31, k0 = kb * 16 + (lane >> 5) * 8;
        const short* s = h ? &lbuf[row][k0] : &hbuf[row][k0];
        short8v val = *reinterpret_cast<const short8v*>(s);
        *reinterpret_cast<short8v*>(&dst[(size_t)u * 8]) = val;
    }
}

// ---------------- argmin: DMA-fed 3-deep pipelined fragment MFMA GEMM -----
// block tile 128 rows x 256 codes, 4 waves each 64x128 (2m x 4n mfma 32x32).
// 24 x 1KB chunks per kb staged by global_load_lds (6 per wave) into a
// 3-buffer circular LDS pipeline; raw s_barrier + counted vmcnt(6) keeps
// ~2 kb-steps of prefetch in flight (covers HBM/L3 latency). MFMA order
// identical to prior rounds -> bit-identical numerics.
__global__ __launch_bounds__(256, 2) void k_argmin(const short* __restrict__ xfrag,
                                                   const short* __restrict__ efrag,
                                                   const float* __restrict__ en2,
                                                   unsigned long long* __restrict__ packed) {
    __shared__ short sbuf[3][12288];      // 3 x 24 KB
    const int tid = threadIdx.x;
    const int w = tid >> 6, l = tid & 63;
    const int wr = w >> 1, wc = w & 1;
    const int l31 = l & 31, lh = l >> 5;

    int bid = blockIdx.x;                 // 1024 blocks
    int xcd = bid & 7, j = bid >> 3;      // j 0..127
    int row0 = (xcd * 32 + (j >> 2)) * 128;
    int c0   = (j & 3) * 256;

    // wave w stages chunks q = s*4 + w (s=0..5); chunk q <-> (g=q>>1, h=q&1)
    // per-lane global src = base_g + (h*512 + l*8) shorts (+ kb*1024 shorts)
    const short* gsrc[6];
    #pragma unroll
    for (int s = 0; s < 6; ++s) {
        int q = s * 4 + w, g = q >> 1, h = q & 1;
        const short* base = (g < 4)
            ? xfrag + (size_t)(row0 / 32 + g) * 32768
            : efrag + (size_t)(c0 / 32 + (g - 4)) * 32768;
        gsrc[s] = base + h * 512 + l * 8;
    }

    f32x16 acc[2][4];
    #pragma unroll
    for (int a = 0; a < 2; ++a)
        #pragma unroll
        for (int b = 0; b < 4; ++b)
            #pragma unroll
            for (int r = 0; r < 16; ++r) acc[a][b][r] = 0.f;

    // prologue: DMA kb=0 -> buf0, kb=1 -> buf1
    #pragma unroll
    for (int s = 0; s < 6; ++s)
        __builtin_amdgcn_global_load_lds((const AS1 void*)gsrc[s],
                                         (AS3 void*)&sbuf[0][(s * 4 + w) * 512],
                                         16, 0, 0);
    #pragma unroll
    for (int s = 0; s < 6; ++s)
        __builtin_amdgcn_global_load_lds((const AS1 void*)(gsrc[s] + 1024),
                                         (AS3 void*)&sbuf[1][(s * 4 + w) * 512],
                                         16, 0, 0);
    asm volatile("s_waitcnt vmcnt(6)" ::: "memory");
    __builtin_amdgcn_s_barrier();
    __builtin_amdgcn_sched_barrier(0);

    #pragma unroll 3
    for (int kb = 0; kb < 30; ++kb) {
        const int cur = kb % 3, nxt = (kb + 2) % 3;
        // issue prefetch for kb+2
        #pragma unroll
        for (int s = 0; s < 6; ++s)
            __builtin_amdgcn_global_load_lds(
                (const AS1 void*)(gsrc[s] + (size_t)(kb + 2) * 1024),
                (AS3 void*)&sbuf[nxt][(s * 4 + w) * 512], 16, 0, 0);
        // compute kb
        {
            short8v ah[2], al[2], bh[4], bl[4];
            const short* sb = sbuf[cur];
            #pragma unroll
            for (int m = 0; m < 2; ++m) {
                int g = wr * 2 + m;
                ah[m] = *reinterpret_cast<const short8v*>(&sb[(g * 2 + 0) * 512 + l * 8]);
                al[m] = *reinterpret_cast<const short8v*>(&sb[(g * 2 + 1) * 512 + l * 8]);
            }
            #pragma unroll
            for (int n = 0; n < 4; ++n) {
                int g = 4 + wc * 4 + n;
                bh[n] = *reinterpret_cast<const short8v*>(&sb[(g * 2 + 0) * 512 + l * 8]);
                bl[n] = *reinterpret_cast<const short8v*>(&sb[(g * 2 + 1) * 512 + l * 8]);
            }
            #pragma unroll
            for (int m = 0; m < 2; ++m)
                #pragma unroll
                for (int n = 0; n < 4; ++n) {
                    acc[m][n] = __builtin_amdgcn_mfma_f32_32x32x16_bf16(
                        ah[m], bh[n], acc[m][n], 0, 0, 0);
                    acc[m][n] = __builtin_amdgcn_mfma_f32_32x32x16_bf16(
                        ah[m], bl[n], acc[m][n], 0, 0, 0);
                    acc[m][n] = __builtin_amdgcn_mfma_f32_32x32x16_bf16(
                        al[m], bh[n], acc[m][n], 0, 0, 0);
                }
        }
        // kb+1 fully resident before next iter reads it; keep kb+2 in flight
        asm volatile("s_waitcnt vmcnt(6) lgkmcnt(0)" ::: "memory");
        __builtin_amdgcn_s_barrier();
        __builtin_amdgcn_sched_barrier(0);
    }

    // epilogue kbs 30, 31 (no further prefetch)
    #pragma unroll
    for (int e = 0; e < 2; ++e) {
        const int kb = 30 + e, cur = kb % 3;
        short8v ah[2], al[2], bh[4], bl[4];
        const short* sb = sbuf[cur];
        #pragma unroll
        for (int m = 0; m < 2; ++m) {
            int g = wr * 2 + m;
            ah[m] = *reinterpret_cast<const short8v*>(&sb[(g * 2 + 0) * 512 + l * 8]);
            al[m] = *reinterpret_cast<const short8v*>(&sb[(g * 2 + 1) * 512 + l * 8]);
        }
        #pragma unroll
        for (int n = 0; n < 4; ++n) {
            int g = 4 + wc * 4 + n;
            bh[n] = *reinterpret_cast<const short8v*>(&sb[(g * 2 + 0) * 512 + l * 8]);
            bl[n] = *reinterpret_cast<const short8v*>(&sb[(g * 2 + 1) * 512 + l * 8]);
        }
        #pragma unroll
        for (int m = 0; m < 2; ++m)
            #pragma unroll
            for (int n = 0; n < 4; ++n) {
                acc[m][n] = __builtin_amdgcn_mfma_f32_32x32x16_bf16(
                    ah[m], bh[n], acc[m][n], 0, 0, 0);
                acc[m][n] = __builtin_amdgcn_mfma_f32_32x32x16_bf16(
                    ah[m], bl[n], acc[m][n], 0, 0, 0);
                acc[m][n] = __builtin_amdgcn_mfma_f32_32x32x16_bf16(
                    al[m], bh[n], acc[m][n], 0, 0, 0);
            }
        if (e == 0) {
            asm volatile("s_waitcnt vmcnt(0) lgkmcnt(0)" ::: "memory");
            __builtin_amdgcn_s_barrier();
            __builtin_amdgcn_sched_barrier(0);
        }
    }

    // epilogue: dist = ||e||^2 - 2 x.e ; D layout: col=l&31,
    // row=(r&3)+8*(r>>2)+4*(l>>5)
    float e2[4];
    #pragma unroll
    for (int n = 0; n < 4; ++n) e2[n] = en2[c0 + wc * 128 + n * 32 + l31];
    #pragma unroll
    for (int m = 0; m < 2; ++m) {
        #pragma unroll
        for (int r = 0; r < 16; ++r) {
            unsigned long long key = 0xFFFFFFFFFFFFFFFFull;
            #pragma unroll
            for (int n = 0; n < 4; ++n) {
                float d = fmaf(-2.f, acc[m][n][r], e2[n]);
                unsigned long long k = pack_key(d, c0 + wc * 128 + n * 32 + l31);
                if (k < key) key = k;
            }
            #pragma unroll
            for (int off = 1; off < 32; off <<= 1) {
                unsigned long long o = __shfl_xor(key, off);
                if (o < key) key = o;
            }
            if (l31 == 0) {
                int grow = row0 + wr * 64 + m * 32 + (r & 3) + 8 * (r >> 2) + 4 * lh;
                atomicMin(&packed[grow], key);
            }
        }
    }
}

// ---------------- unpack idx + histogram ----------------
__global__ __launch_bounds__(256) void k_hist(const unsigned long long* __restrict__ packed,
                                              int* __restrict__ idx,
                                              int* __restrict__ counts) {
    __shared__ int h[KC];
    for (int i = threadIdx.x; i < KC; i += 256) h[i] = 0;
    __syncthreads();
    int g = blockIdx.x * 256 + threadIdx.x;
    int c = (int)(unsigned)(packed[g] & 0xFFFFFFFFull);
    idx[g] = c;
    atomicAdd(&h[c], 1);
    __syncthreads();
    for (int i = threadIdx.x; i < KC; i += 256)
        if (h[i]) atomicAdd(&counts[i], h[i]);
}

// ---------------- smoothing, perplexity, prefix sums ----------------
__global__ __launch_bounds__(1024) void k_meta(const int* __restrict__ counts,
                                               const float* __restrict__ ema_cs,
                                               float* __restrict__ smoothed,
                                               int* __restrict__ offsets,
                                               int* __restrict__ cursor,
                                               float* __restrict__ perp_out) {
    __shared__ float red[KC];
    __shared__ int sc[KC];
    int t = threadIdx.x;
    int cnt = counts[t];
    float cs = ema_cs[t] * 0.99f + 0.01f * (float)cnt;
    red[t] = cs; __syncthreads();
    for (int s = 512; s; s >>= 1) { if (t < s) red[t] += red[t + s]; __syncthreads(); }
    float n = red[0];
    __syncthreads();
    float sm = (cs + 1e-5f) / (n + 1024.f * 1e-5f) * n;
    smoothed[t] = sm;
    float p = (float)cnt / 32768.f;
    red[t] = p * logf(p + 1e-10f);
    __syncthreads();
    for (int s = 512; s; s >>= 1) { if (t < s) red[t] += red[t + s]; __syncthreads(); }
    if (!t) perp_out[0] = expf(-red[0]);
    sc[t] = cnt; __syncthreads();
    for (int s = 1; s < KC; s <<= 1) {
        int v = (t >= s) ? sc[t - s] : 0;
        __syncthreads();
        sc[t] += v;
        __syncthreads();
    }
    int off = sc[t] - cnt;
    offsets[t] = off;
    cursor[t] = off;
}

// ---------------- CSR bucket scatter ----------------
__global__ __launch_bounds__(256) void k_scatter(const int* __restrict__ idx,
                                                 int* __restrict__ cursor,
                                                 int* __restrict__ bucket) {
    int g = blockIdx.x * 256 + threadIdx.x;
    int c = idx[g];
    int pos = atomicAdd(&cursor[c], 1);
    bucket[pos] = g;
}

// ---------------- segment-sum + new embedding (LDS-staged, unrolled) ------
__global__ __launch_bounds__(256) void k_dw(const float* __restrict__ x,
                                            const float* __restrict__ ema_w,
                                            const int* __restrict__ offsets,
                                            const int* __restrict__ counts,
                                            const int* __restrict__ bucket,
                                            const float* __restrict__ smoothed,
                                            float* __restrict__ newE) {
    __shared__ int rows[256];
    int k = blockIdx.x, t = threadIdx.x;
    int beg = offsets[k], m = counts[k];
    float a0 = 0.f, a1 = 0.f;
    for (int base = 0; base < m; base += 256) {
        int n = min(256, m - base);
        __syncthreads();
        if (t < n) rows[t] = bucket[beg + base + t];
        __syncthreads();
        int i = 0;
        for (; i + 4 <= n; i += 4) {
            int r0 = rows[i], r1 = rows[i + 1], r2 = rows[i + 2], r3 = rows[i + 3];
            float v00 = x[(size_t)r0 * DIM + t];
            float v01 = x[(size_t)r0 * DIM + t + 256];
            float v10 = x[(size_t)r1 * DIM + t];
            float v11 = x[(size_t)r1 * DIM + t + 256];
            float v20 = x[(size_t)r2 * DIM + t];
            float v21 = x[(size_t)r2 * DIM + t + 256];
            float v30 = x[(size_t)r3 * DIM + t];
            float v31 = x[(size_t)r3 * DIM + t + 256];
            a0 += v00 + v10 + v20 + v30;
            a1 += v01 + v11 + v21 + v31;
        }
        for (; i < n; ++i) {
            int r = rows[i];
            a0 += x[(size_t)r * DIM + t];
            a1 += x[(size_t)r * DIM + t + 256];
        }
    }
    float sm = smoothed[k];
    newE[(size_t)k * DIM + t]       = (ema_w[(size_t)k * DIM + t]       * 0.99f + 0.01f * a0) / sm;
    newE[(size_t)k * DIM + t + 256] = (ema_w[(size_t)k * DIM + t + 256] * 0.99f + 0.01f * a1) / sm;
}

// ---------------- fused quantized (STE) + one-hot + loss partials ---------
__global__ __launch_bounds__(256) void k_qe(const float* __restrict__ x,
                                            const int* __restrict__ idx,
                                            const float* __restrict__ newE,
                                            float* __restrict__ outq,
                                            float* __restrict__ enc,
                                            float* __restrict__ partials) {
    int b = blockIdx.x, t = threadIdx.x;
    int row8 = b * 8;
    float lp = 0.f;
    #pragma unroll
    for (int it = 0; it < 4; ++it) {
        int slot = t + it * 256;
        int r = slot >> 7;
        int c4 = (slot & 127) * 4;
        int row = row8 + r;
        int code = idx[row];
        float4 in = *reinterpret_cast<const float4*>(&x[(size_t)row * DIM + c4]);
        float4 q  = *reinterpret_cast<const float4*>(&newE[(size_t)code * DIM + c4]);
        float4 d;
        d.x = q.x - in.x; d.y = q.y - in.y; d.z = q.z - in.z; d.w = q.w - in.w;
        float4 o;
        o.x = in.x + d.x; o.y = in.y + d.y; o.z = in.z + d.z; o.w = in.w + d.w;
        *reinterpret_cast<float4*>(&outq[(size_t)row * DIM + c4]) = o;
        lp += d.x*d.x + d.y*d.y + d.z*d.z + d.w*d.w;
    }
    {
        int er = row8 + (t >> 5);
        int l32 = t & 31;
        int one = idx[er];
        float4* dst = reinterpret_cast<float4*>(enc + (size_t)er * KC);
        #pragma unroll
        for (int s = 0; s < 8; ++s) {
            int c4 = l32 + s * 32;
            int base = c4 * 4;
            float4 v;
            v.x = (one == base)     ? 1.f : 0.f;
            v.y = (one == base + 1) ? 1.f : 0.f;
            v.z = (one == base + 2) ? 1.f : 0.f;
            v.w = (one == base + 3) ? 1.f : 0.f;
            dst[c4] = v;
        }
    }
    #pragma unroll
    for (int off = 32; off; off >>= 1) lp += __shfl_xor(lp, off);
    __shared__ float wr[4];
    int lane = t & 63, w = t >> 6;
    if (!lane) wr[w] = lp;
    __syncthreads();
    if (t == 0) partials[b] = wr[0] + wr[1] + wr[2] + wr[3];
}

__global__ __launch_bounds__(256) void k_lossfin(const float* __restrict__ partials,
                                                 float* __restrict__ out0) {
    __shared__ double red[256];
    double s = 0.0;
    for (int i = threadIdx.x; i < 4096; i += 256) s += (double)partials[i];
    red[threadIdx.x] = s; __syncthreads();
    for (int st = 128; st; st >>= 1) {
        if (threadIdx.x < st) red[threadIdx.x] += red[threadIdx.x + st];
        __syncthreads();
    }
    if (!threadIdx.x) out0[0] = (float)(0.25 * red[0] / 16777216.0);
}

extern "C" void kernel_launch(void* const* d_in, const int* in_sizes, int n_in,
                              void* d_out, int out_size, void* d_ws, size_t ws_size,
                              hipStream_t stream) {
    const float* x   = (const float*)d_in[0];
    const float* E   = (const float*)d_in[1];
    const float* ecs = (const float*)d_in[2];
    const float* emw = (const float*)d_in[3];
    float* out = (float*)d_out;

    char* ws = (char*)d_ws;
    int*   idx      = (int*)(ws + 0);                  // 128 KB
    int*   bucket   = (int*)(ws + 131072);             // 128 KB
    float* en2      = (float*)(ws + 262144);           // 4 KB
    int*   counts   = (int*)(ws + 266240);             // 4 KB
    int*   offsets  = (int*)(ws + 270336);             // 4 KB
    int*   cursor   = (int*)(ws + 274432);             // 4 KB
    float* smoothed = (float*)(ws + 278528);           // 4 KB
    float* newE     = (float*)(ws + 282624);           // 2 MB
    float* partials = (float*)(ws + 282624 + 2097152); // 16 KB
    unsigned long long* packed = (unsigned long long*)newE;  // dead before k_dw

    float* out_loss = out;
    float* out_q    = out + 1;
    float* out_perp = out + 16777217;
    float* out_enc  = out + 16777218;

    // fragment scratch lives in out_enc (128 MB, rewritten by k_qe later):
    // xfrag 64 MB + efrag 2 MB
    short* xfrag = (short*)out_enc;
    short* efrag = xfrag + (size_t)NROWS * DIM * 2;

    hipMemsetAsync(counts, 0, KC * sizeof(int), stream);
    hipMemsetAsync(packed, 0xFF, NROWS * sizeof(unsigned long long), stream);

    k_enorm  <<<KC / 4, 256, 0, stream>>>(E, en2);
    k_split  <<<NROWS / 32 + KC / 32, 256, 0, stream>>>(x, E, xfrag, efrag);
    k_argmin <<<(NROWS / 128) * 4, 256, 0, stream>>>(xfrag, efrag, en2, packed);
    k_hist   <<<NROWS / 256, 256, 0, stream>>>(packed, idx, counts);
    k_meta   <<<1, 1024, 0, stream>>>(counts, ecs, smoothed, offsets, cursor, out_perp);
    k_scatter<<<NROWS / 256, 256, 0, stream>>>(idx, cursor, bucket);
    k_dw     <<<KC, 256, 0, stream>>>(x, emw, offsets, counts, bucket, smoothed, newE);
    k_qe     <<<NROWS / 8, 256, 0, stream>>>(x, idx, newE, out_q, out_enc, partials);
    k_lossfin<<<1, 256, 0, stream>>>(partials, out_loss);
}

// Round 8
// 301.132 us; speedup vs baseline: 3.0560x; 1.0296x over previous
//
#include <hip/hip_runtime.h>

#define NROWS 32768
#define DIM   512
#define KC    1024

typedef __attribute__((ext_vector_type(8)))  short short8v;
typedef __attribute__((ext_vector_type(16))) float f32x16;

#define AS1 __attribute__((address_space(1)))
#define AS3 __attribute__((address_space(3)))

// ---------------- e_norm2: ||E[k]||^2 (exact fp32) ----------------
__global__ __launch_bounds__(256) void k_enorm(const float* __restrict__ E,
                                               float* __restrict__ en2) {
    int w = threadIdx.x >> 6, lane = threadIdx.x & 63;
    int c = blockIdx.x * 4 + w;
    const float* row = E + (size_t)c * DIM;
    float4 a = *reinterpret_cast<const float4*>(&row[lane * 8]);
    float4 b = *reinterpret_cast<const float4*>(&row[lane * 8 + 4]);
    float s = a.x*a.x + a.y*a.y + a.z*a.z + a.w*a.w
            + b.x*b.x + b.y*b.y + b.z*b.z + b.w*b.w;
    #pragma unroll
    for (int off = 32; off; off >>= 1) s += __shfl_xor(s, off);
    if (!lane) en2[c] = s;
}

// RTN float -> bf16(short), plus residual bf16
__device__ __forceinline__ void split_bf16(float v, short& hi, short& lo) {
    unsigned u = __float_as_uint(v);
    unsigned r = u + 0x7FFFu + ((u >> 16) & 1u);
    hi = (short)(r >> 16);
    float hif = __uint_as_float(r & 0xFFFF0000u);
    float rem = v - hif;
    unsigned u2 = __float_as_uint(rem);
    unsigned r2 = u2 + 0x7FFFu + ((u2 >> 16) & 1u);
    lo = (short)(r2 >> 16);
}

__device__ __forceinline__ unsigned long long pack_key(float d, int c) {
    unsigned u = __float_as_uint(d);
    u = (u & 0x80000000u) ? ~u : (u | 0x80000000u);   // monotone for min
    return ((unsigned long long)u << 32) | (unsigned)c;
}

// ---------------- split x and E to bf16 hi/lo in MFMA fragment layout -----
// per 32-row group: [kb 0..31][h 0..1][lane 0..63][8 shorts]
// fragment: lane l holds rows l&31, k = kb*16 + (l>>5)*8 .. +7
// side duties (saves 2 memset dispatches): block 0 zeros counts,
// E-blocks init packed to 0xFF.
__global__ __launch_bounds__(256) void k_split(const float* __restrict__ x,
                                               const float* __restrict__ E,
                                               short* __restrict__ xfrag,
                                               short* __restrict__ efrag,
                                               int* __restrict__ counts,
                                               unsigned long long* __restrict__ packed) {
    __shared__ short hbuf[32][520];
    __shared__ short lbuf[32][520];
    int b = blockIdx.x, t = threadIdx.x;
    const float* src;
    short* dst;
    if (b < NROWS / 32) {
        src = x + (size_t)b * 32 * DIM;
        dst = xfrag + (size_t)b * 32768;
        if (b == 0) {
            #pragma unroll
            for (int i = 0; i < 4; ++i) counts[t + i * 256] = 0;
        }
    } else {
        int eb = b - NROWS / 32;
        src = E + (size_t)eb * 32 * DIM;
        dst = efrag + (size_t)eb * 32768;
        unsigned long long* p = packed + eb * 1024;
        #pragma unroll
        for (int i = 0; i < 4; ++i) p[t + i * 256] = 0xFFFFFFFFFFFFFFFFull;
    }
    #pragma unroll
    for (int f = 0; f < 16; ++f) {
        int u = t + f * 256;
        int row = u >> 7, c4 = (u & 127) * 4;
        float4 v = *reinterpret_cast<const float4*>(&src[row * DIM + c4]);
        short4 h4, l4;
        split_bf16(v.x, h4.x, l4.x); split_bf16(v.y, h4.y, l4.y);
        split_bf16(v.z, h4.z, l4.z); split_bf16(v.w, h4.w, l4.w);
        *reinterpret_cast<short4*>(&hbuf[row][c4]) = h4;
        *reinterpret_cast<short4*>(&lbuf[row][c4]) = l4;
    }
    __syncthreads();
    #pragma unroll
    for (int f = 0; f < 16; ++f) {
        int u = t + f * 256;
        int lane = u & 63, h = (u >> 6) & 1, kb = u >> 7;
        int row = lane & 31, k0 = kb * 16 + (lane >> 5) * 8;
        const short* s = h ? &lbuf[row][k0] : &hbuf[row][k0];
        short8v val = *reinterpret_cast<const short8v*>(s);
        *reinterpret_cast<short8v*>(&dst[(size_t)u * 8]) = val;
    }
}

// ---------------- argmin: DMA-fed 3-deep pipelined fragment MFMA GEMM -----
// block tile 128 rows x 256 codes, 4 waves each 64x128 (2m x 4n mfma 32x32).
// 24 x 1KB chunks per kb staged by global_load_lds (6 per wave) into a
// 3-buffer circular LDS pipeline; raw s_barrier + counted vmcnt(6) keeps
// ~2 kb-steps of prefetch in flight. MFMA order identical to prior rounds.
__global__ __launch_bounds__(256, 2) void k_argmin(const short* __restrict__ xfrag,
                                                   const short* __restrict__ efrag,
                                                   const float* __restrict__ en2,
                                                   unsigned long long* __restrict__ packed) {
    __shared__ short sbuf[3][12288];      // 3 x 24 KB
    const int tid = threadIdx.x;
    const int w = tid >> 6, l = tid & 63;
    const int wr = w >> 1, wc = w & 1;
    const int l31 = l & 31, lh = l >> 5;

    int bid = blockIdx.x;                 // 1024 blocks
    int xcd = bid & 7, j = bid >> 3;      // j 0..127
    int row0 = (xcd * 32 + (j >> 2)) * 128;
    int c0   = (j & 3) * 256;

    const short* gsrc[6];
    #pragma unroll
    for (int s = 0; s < 6; ++s) {
        int q = s * 4 + w, g = q >> 1, h = q & 1;
        const short* base = (g < 4)
            ? xfrag + (size_t)(row0 / 32 + g) * 32768
            : efrag + (size_t)(c0 / 32 + (g - 4)) * 32768;
        gsrc[s] = base + h * 512 + l * 8;
    }

    f32x16 acc[2][4];
    #pragma unroll
    for (int a = 0; a < 2; ++a)
        #pragma unroll
        for (int b = 0; b < 4; ++b)
            #pragma unroll
            for (int r = 0; r < 16; ++r) acc[a][b][r] = 0.f;

    #pragma unroll
    for (int s = 0; s < 6; ++s)
        __builtin_amdgcn_global_load_lds((const AS1 void*)gsrc[s],
                                         (AS3 void*)&sbuf[0][(s * 4 + w) * 512],
                                         16, 0, 0);
    #pragma unroll
    for (int s = 0; s < 6; ++s)
        __builtin_amdgcn_global_load_lds((const AS1 void*)(gsrc[s] + 1024),
                                         (AS3 void*)&sbuf[1][(s * 4 + w) * 512],
                                         16, 0, 0);
    asm volatile("s_waitcnt vmcnt(6)" ::: "memory");
    __builtin_amdgcn_s_barrier();

    #pragma unroll 3
    for (int kb = 0; kb < 30; ++kb) {
        const int cur = kb % 3, nxt = (kb + 2) % 3;
        #pragma unroll
        for (int s = 0; s < 6; ++s)
            __builtin_amdgcn_global_load_lds(
                (const AS1 void*)(gsrc[s] + (size_t)(kb + 2) * 1024),
                (AS3 void*)&sbuf[nxt][(s * 4 + w) * 512], 16, 0, 0);
        {
            short8v ah[2], al[2], bh[4], bl[4];
            const short* sb = sbuf[cur];
            #pragma unroll
            for (int m = 0; m < 2; ++m) {
                int g = wr * 2 + m;
                ah[m] = *reinterpret_cast<const short8v*>(&sb[(g * 2 + 0) * 512 + l * 8]);
                al[m] = *reinterpret_cast<const short8v*>(&sb[(g * 2 + 1) * 512 + l * 8]);
            }
            #pragma unroll
            for (int n = 0; n < 4; ++n) {
                int g = 4 + wc * 4 + n;
                bh[n] = *reinterpret_cast<const short8v*>(&sb[(g * 2 + 0) * 512 + l * 8]);
                bl[n] = *reinterpret_cast<const short8v*>(&sb[(g * 2 + 1) * 512 + l * 8]);
            }
            #pragma unroll
            for (int m = 0; m < 2; ++m)
                #pragma unroll
                for (int n = 0; n < 4; ++n) {
                    acc[m][n] = __builtin_amdgcn_mfma_f32_32x32x16_bf16(
                        ah[m], bh[n], acc[m][n], 0, 0, 0);
                    acc[m][n] = __builtin_amdgcn_mfma_f32_32x32x16_bf16(
                        ah[m], bl[n], acc[m][n], 0, 0, 0);
                    acc[m][n] = __builtin_amdgcn_mfma_f32_32x32x16_bf16(
                        al[m], bh[n], acc[m][n], 0, 0, 0);
                }
        }
        // all this wave's ds_reads of buf cur must retire before the barrier
        // (next iter's DMA overwrites cur); keep kb+2's 6 loads in flight
        asm volatile("s_waitcnt vmcnt(6) lgkmcnt(0)" ::: "memory");
        __builtin_amdgcn_s_barrier();
    }

    #pragma unroll
    for (int e = 0; e < 2; ++e) {
        const int kb = 30 + e, cur = kb % 3;
        short8v ah[2], al[2], bh[4], bl[4];
        const short* sb = sbuf[cur];
        #pragma unroll
        for (int m = 0; m < 2; ++m) {
            int g = wr * 2 + m;
            ah[m] = *reinterpret_cast<const short8v*>(&sb[(g * 2 + 0) * 512 + l * 8]);
            al[m] = *reinterpret_cast<const short8v*>(&sb[(g * 2 + 1) * 512 + l * 8]);
        }
        #pragma unroll
        for (int n = 0; n < 4; ++n) {
            int g = 4 + wc * 4 + n;
            bh[n] = *reinterpret_cast<const short8v*>(&sb[(g * 2 + 0) * 512 + l * 8]);
            bl[n] = *reinterpret_cast<const short8v*>(&sb[(g * 2 + 1) * 512 + l * 8]);
        }
        #pragma unroll
        for (int m = 0; m < 2; ++m)
            #pragma unroll
            for (int n = 0; n < 4; ++n) {
                acc[m][n] = __builtin_amdgcn_mfma_f32_32x32x16_bf16(
                    ah[m], bh[n], acc[m][n], 0, 0, 0);
                acc[m][n] = __builtin_amdgcn_mfma_f32_32x32x16_bf16(
                    ah[m], bl[n], acc[m][n], 0, 0, 0);
                acc[m][n] = __builtin_amdgcn_mfma_f32_32x32x16_bf16(
                    al[m], bh[n], acc[m][n], 0, 0, 0);
            }
        if (e == 0) {
            asm volatile("s_waitcnt vmcnt(0) lgkmcnt(0)" ::: "memory");
            __builtin_amdgcn_s_barrier();
        }
    }

    // epilogue: dist = ||e||^2 - 2 x.e ; D layout: col=l&31,
    // row=(r&3)+8*(r>>2)+4*(l>>5)
    float e2[4];
    #pragma unroll
    for (int n = 0; n < 4; ++n) e2[n] = en2[c0 + wc * 128 + n * 32 + l31];
    #pragma unroll
    for (int m = 0; m < 2; ++m) {
        #pragma unroll
        for (int r = 0; r < 16; ++r) {
            unsigned long long key = 0xFFFFFFFFFFFFFFFFull;
            #pragma unroll
            for (int n = 0; n < 4; ++n) {
                float d = fmaf(-2.f, acc[m][n][r], e2[n]);
                unsigned long long k = pack_key(d, c0 + wc * 128 + n * 32 + l31);
                if (k < key) key = k;
            }
            #pragma unroll
            for (int off = 1; off < 32; off <<= 1) {
                unsigned long long o = __shfl_xor(key, off);
                if (o < key) key = o;
            }
            if (l31 == 0) {
                int grow = row0 + wr * 64 + m * 32 + (r & 3) + 8 * (r >> 2) + 4 * lh;
                atomicMin(&packed[grow], key);
            }
        }
    }
}

// ---------------- unpack idx + histogram ----------------
__global__ __launch_bounds__(256) void k_hist(const unsigned long long* __restrict__ packed,
                                              int* __restrict__ idx,
                                              int* __restrict__ counts) {
    __shared__ int h[KC];
    for (int i = threadIdx.x; i < KC; i += 256) h[i] = 0;
    __syncthreads();
    int g = blockIdx.x * 256 + threadIdx.x;
    int c = (int)(unsigned)(packed[g] & 0xFFFFFFFFull);
    idx[g] = c;
    atomicAdd(&h[c], 1);
    __syncthreads();
    for (int i = threadIdx.x; i < KC; i += 256)
        if (h[i]) atomicAdd(&counts[i], h[i]);
}

// ---------------- smoothing, perplexity, prefix sums (1-barrier) ----------
__global__ __launch_bounds__(1024) void k_meta(const int* __restrict__ counts,
                                               const float* __restrict__ ema_cs,
                                               float* __restrict__ smoothed,
                                               int* __restrict__ offsets,
                                               int* __restrict__ cursor,
                                               float* __restrict__ perp_out) {
    __shared__ float ws1[16], ws2[16];
    __shared__ int wsum[16];
    int t = threadIdx.x, lane = t & 63, w = t >> 6;
    int cnt = counts[t];
    float cs = ema_cs[t] * 0.99f + 0.01f * (float)cnt;
    float p = (float)cnt / 32768.f;
    float v1 = cs, v2 = p * logf(p + 1e-10f);
    #pragma unroll
    for (int off = 32; off; off >>= 1) {
        v1 += __shfl_xor(v1, off);
        v2 += __shfl_xor(v2, off);
    }
    int s = cnt;
    #pragma unroll
    for (int off = 1; off < 64; off <<= 1) {
        int u = __shfl_up(s, off);
        if (lane >= off) s += u;
    }
    if (lane == 0) { ws1[w] = v1; ws2[w] = v2; }
    if (lane == 63) wsum[w] = s;
    __syncthreads();
    float n = 0.f;
    #pragma unroll
    for (int i = 0; i < 16; ++i) n += ws1[i];
    smoothed[t] = (cs + 1e-5f) / (n + 1024.f * 1e-5f) * n;
    if (t == 0) {
        float sp = 0.f;
        #pragma unroll
        for (int i = 0; i < 16; ++i) sp += ws2[i];
        perp_out[0] = expf(-sp);
    }
    int wo = 0;
    for (int i = 0; i < 16; ++i) if (i < w) wo += wsum[i];
    int off_ = wo + s - cnt;   // exclusive prefix (exact int)
    offsets[t] = off_;
    cursor[t] = off_;
}

// ---------------- CSR bucket scatter ----------------
__global__ __launch_bounds__(256) void k_scatter(const int* __restrict__ idx,
                                                 int* __restrict__ cursor,
                                                 int* __restrict__ bucket) {
    int g = blockIdx.x * 256 + threadIdx.x;
    int c = idx[g];
    int pos = atomicAdd(&cursor[c], 1);
    bucket[pos] = g;
}

// ---------------- segment-sum + new embedding (2 half-dim blocks/code) ----
__global__ __launch_bounds__(256) void k_dw(const float* __restrict__ x,
                                            const float* __restrict__ ema_w,
                                            const int* __restrict__ offsets,
                                            const int* __restrict__ counts,
                                            const int* __restrict__ bucket,
                                            const float* __restrict__ smoothed,
                                            float* __restrict__ newE) {
    __shared__ int rows[256];
    int k = blockIdx.x >> 1, half = blockIdx.x & 1, t = threadIdx.x;
    int d = half * 256 + t;
    int beg = offsets[k], m = counts[k];
    float a = 0.f;
    for (int base = 0; base < m; base += 256) {
        int n = min(256, m - base);
        __syncthreads();
        if (t < n) rows[t] = bucket[beg + base + t];
        __syncthreads();
        int i = 0;
        for (; i + 4 <= n; i += 4) {
            float v0 = x[(size_t)rows[i]     * DIM + d];
            float v1 = x[(size_t)rows[i + 1] * DIM + d];
            float v2 = x[(size_t)rows[i + 2] * DIM + d];
            float v3 = x[(size_t)rows[i + 3] * DIM + d];
            a += v0 + v1 + v2 + v3;
        }
        for (; i < n; ++i) a += x[(size_t)rows[i] * DIM + d];
    }
    newE[(size_t)k * DIM + d] =
        (ema_w[(size_t)k * DIM + d] * 0.99f + 0.01f * a) / smoothed[k];
}

// ---------------- fused quantized (STE) + one-hot + loss partials ---------
__global__ __launch_bounds__(256) void k_qe(const float* __restrict__ x,
                                            const int* __restrict__ idx,
                                            const float* __restrict__ newE,
                                            float* __restrict__ outq,
                                            float* __restrict__ enc,
                                            float* __restrict__ partials) {
    int b = blockIdx.x, t = threadIdx.x;
    int row8 = b * 8;
    float lp = 0.f;
    #pragma unroll
    for (int it = 0; it < 4; ++it) {
        int slot = t + it * 256;
        int r = slot >> 7;
        int c4 = (slot & 127) * 4;
        int row = row8 + r;
        int code = idx[row];
        float4 in = *reinterpret_cast<const float4*>(&x[(size_t)row * DIM + c4]);
        float4 q  = *reinterpret_cast<const float4*>(&newE[(size_t)code * DIM + c4]);
        float4 d;
        d.x = q.x - in.x; d.y = q.y - in.y; d.z = q.z - in.z; d.w = q.w - in.w;
        float4 o;
        o.x = in.x + d.x; o.y = in.y + d.y; o.z = in.z + d.z; o.w = in.w + d.w;
        *reinterpret_cast<float4*>(&outq[(size_t)row * DIM + c4]) = o;
        lp += d.x*d.x + d.y*d.y + d.z*d.z + d.w*d.w;
    }
    {
        int er = row8 + (t >> 5);
        int l32 = t & 31;
        int one = idx[er];
        float4* dst = reinterpret_cast<float4*>(enc + (size_t)er * KC);
        #pragma unroll
        for (int s = 0; s < 8; ++s) {
            int c4 = l32 + s * 32;
            int base = c4 * 4;
            float4 v;
            v.x = (one == base)     ? 1.f : 0.f;
            v.y = (one == base + 1) ? 1.f : 0.f;
            v.z = (one == base + 2) ? 1.f : 0.f;
            v.w = (one == base + 3) ? 1.f : 0.f;
            dst[c4] = v;
        }
    }
    #pragma unroll
    for (int off = 32; off; off >>= 1) lp += __shfl_xor(lp, off);
    __shared__ float wr[4];
    int lane = t & 63, w = t >> 6;
    if (!lane) wr[w] = lp;
    __syncthreads();
    if (t == 0) partials[b] = wr[0] + wr[1] + wr[2] + wr[3];
}

__global__ __launch_bounds__(256) void k_lossfin(const float* __restrict__ partials,
                                                 float* __restrict__ out0) {
    __shared__ double red[256];
    double s = 0.0;
    for (int i = threadIdx.x; i < 4096; i += 256) s += (double)partials[i];
    red[threadIdx.x] = s; __syncthreads();
    for (int st = 128; st; st >>= 1) {
        if (threadIdx.x < st) red[threadIdx.x] += red[threadIdx.x + st];
        __syncthreads();
    }
    if (!threadIdx.x) out0[0] = (float)(0.25 * red[0] / 16777216.0);
}

extern "C" void kernel_launch(void* const* d_in, const int* in_sizes, int n_in,
                              void* d_out, int out_size, void* d_ws, size_t ws_size,
                              hipStream_t stream) {
    const float* x   = (const float*)d_in[0];
    const float* E   = (const float*)d_in[1];
    const float* ecs = (const float*)d_in[2];
    const float* emw = (const float*)d_in[3];
    float* out = (float*)d_out;

    char* ws = (char*)d_ws;
    int*   idx      = (int*)(ws + 0);                  // 128 KB
    int*   bucket   = (int*)(ws + 131072);             // 128 KB
    float* en2      = (float*)(ws + 262144);           // 4 KB
    int*   counts   = (int*)(ws + 266240);             // 4 KB
    int*   offsets  = (int*)(ws + 270336);             // 4 KB
    int*   cursor   = (int*)(ws + 274432);             // 4 KB
    float* smoothed = (float*)(ws + 278528);           // 4 KB
    float* newE     = (float*)(ws + 282624);           // 2 MB
    float* partials = (float*)(ws + 282624 + 2097152); // 16 KB
    unsigned long long* packed = (unsigned long long*)newE;  // dead before k_dw

    float* out_loss = out;
    float* out_q    = out + 1;
    float* out_perp = out + 16777217;
    float* out_enc  = out + 16777218;

    // fragment scratch lives in out_enc (128 MB, rewritten by k_qe later):
    short* xfrag = (short*)out_enc;
    short* efrag = xfrag + (size_t)NROWS * DIM * 2;

    k_enorm  <<<KC / 4, 256, 0, stream>>>(E, en2);
    k_split  <<<NROWS / 32 + KC / 32, 256, 0, stream>>>(x, E, xfrag, efrag,
                                                        counts, packed);
    k_argmin <<<(NROWS / 128) * 4, 256, 0, stream>>>(xfrag, efrag, en2, packed);
    k_hist   <<<NROWS / 256, 256, 0, stream>>>(packed, idx, counts);
    k_meta   <<<1, 1024, 0, stream>>>(counts, ecs, smoothed, offsets, cursor, out_perp);
    k_scatter<<<NROWS / 256, 256, 0, stream>>>(idx, cursor, bucket);
    k_dw     <<<KC * 2, 256, 0, stream>>>(x, emw, offsets, counts, bucket, smoothed, newE);
    k_qe     <<<NROWS / 8, 256, 0, stream>>>(x, idx, newE, out_q, out_enc, partials);
    k_lossfin<<<1, 256, 0, stream>>>(partials, out_loss);
}

// Round 9
// 292.363 us; speedup vs baseline: 3.1476x; 1.0300x over previous
//
#include <hip/hip_runtime.h>

#define NROWS 32768
#define DIM   512
#define KC    1024

typedef __attribute__((ext_vector_type(8)))  short short8v;
typedef __attribute__((ext_vector_type(16))) float f32x16;

#define AS1 __attribute__((address_space(1)))
#define AS3 __attribute__((address_space(3)))

// RTN float -> bf16(short), plus residual bf16
__device__ __forceinline__ void split_bf16(float v, short& hi, short& lo) {
    unsigned u = __float_as_uint(v);
    unsigned r = u + 0x7FFFu + ((u >> 16) & 1u);
    hi = (short)(r >> 16);
    float hif = __uint_as_float(r & 0xFFFF0000u);
    float rem = v - hif;
    unsigned u2 = __float_as_uint(rem);
    unsigned r2 = u2 + 0x7FFFu + ((u2 >> 16) & 1u);
    lo = (short)(r2 >> 16);
}

__device__ __forceinline__ void conv8(const float4 a, const float4 b,
                                      short8v& hi, short8v& lo) {
    short h, l;
    split_bf16(a.x, h, l); hi[0] = h; lo[0] = l;
    split_bf16(a.y, h, l); hi[1] = h; lo[1] = l;
    split_bf16(a.z, h, l); hi[2] = h; lo[2] = l;
    split_bf16(a.w, h, l); hi[3] = h; lo[3] = l;
    split_bf16(b.x, h, l); hi[4] = h; lo[4] = l;
    split_bf16(b.y, h, l); hi[5] = h; lo[5] = l;
    split_bf16(b.z, h, l); hi[6] = h; lo[6] = l;
    split_bf16(b.w, h, l); hi[7] = h; lo[7] = l;
}

__device__ __forceinline__ unsigned long long pack_key(float d, int c) {
    unsigned u = __float_as_uint(d);
    u = (u & 0x80000000u) ? ~u : (u | 0x80000000u);   // monotone for min
    return ((unsigned long long)u << 32) | (unsigned)c;
}

// ---------------- E prep: frag-convert + en2 + inits (32 blocks) ----------
// efrag per 32-row group: [kb 0..31][h 0..1][lane 0..63][8 shorts]
__global__ __launch_bounds__(256) void k_eprep(const float* __restrict__ E,
                                               short* __restrict__ efrag,
                                               float* __restrict__ en2,
                                               int* __restrict__ counts,
                                               unsigned long long* __restrict__ packed) {
    __shared__ short hbuf[32][520];
    __shared__ short lbuf[32][520];
    int b = blockIdx.x, t = threadIdx.x;
    const float* src = E + (size_t)b * 32 * DIM;
    short* dst = efrag + (size_t)b * 32768;

    unsigned long long* p = packed + b * 1024;
    #pragma unroll
    for (int i = 0; i < 4; ++i) p[t + i * 256] = 0xFFFFFFFFFFFFFFFFull;
    if (b == 0) {
        #pragma unroll
        for (int i = 0; i < 4; ++i) counts[t + i * 256] = 0;
    }

    #pragma unroll
    for (int f = 0; f < 16; ++f) {
        int u = t + f * 256;
        int row = u >> 7, c4 = (u & 127) * 4;
        float4 v = *reinterpret_cast<const float4*>(&src[row * DIM + c4]);
        short4 h4, l4;
        split_bf16(v.x, h4.x, l4.x); split_bf16(v.y, h4.y, l4.y);
        split_bf16(v.z, h4.z, l4.z); split_bf16(v.w, h4.w, l4.w);
        *reinterpret_cast<short4*>(&hbuf[row][c4]) = h4;
        *reinterpret_cast<short4*>(&lbuf[row][c4]) = l4;
    }
    __syncthreads();
    #pragma unroll
    for (int f = 0; f < 16; ++f) {
        int u = t + f * 256;
        int lane = u & 63, h = (u >> 6) & 1, kb = u >> 7;
        int row = lane & 31, k0 = kb * 16 + (lane >> 5) * 8;
        const short* s = h ? &lbuf[row][k0] : &hbuf[row][k0];
        short8v val = *reinterpret_cast<const short8v*>(s);
        *reinterpret_cast<short8v*>(&dst[(size_t)u * 8]) = val;
    }

    // en2: wave w handles codes b*32 + w*8 .. +7 (same per-code math as before)
    int w = t >> 6, lane = t & 63;
    for (int cc = 0; cc < 8; ++cc) {
        int c = b * 32 + w * 8 + cc;
        const float* row = E + (size_t)c * DIM;
        float4 a = *reinterpret_cast<const float4*>(&row[lane * 8]);
        float4 bb = *reinterpret_cast<const float4*>(&row[lane * 8 + 4]);
        float s = a.x*a.x + a.y*a.y + a.z*a.z + a.w*a.w
                + bb.x*bb.x + bb.y*bb.y + bb.z*bb.z + bb.w*bb.w;
        #pragma unroll
        for (int off = 32; off; off >>= 1) s += __shfl_xor(s, off);
        if (!lane) en2[c] = s;
    }
}

// ---------------- argmin: x-direct, DMA-B, 3-deep pipelined MFMA GEMM -----
// block tile 128 rows x 256 codes, 4 waves each 64x128 (2m x 4n mfma 32x32).
// A (x): fp32 loaded per-wave per-kb, split to bf16 hi/lo in VGPRs, ds_write
// into frag slots 0..7. B (efrag): 16 x 1KB chunks DMA'd (4/wave) into slots
// 8..23. 3-buffer pipeline: issue A(kb+2) then B(kb+2); vmcnt(4) after MFMA
// guarantees A(kb+2) arrived AND B(kb+1) complete. Numerics bit-identical.
__global__ __launch_bounds__(256, 2) void k_argmin(const float* __restrict__ x,
                                                   const short* __restrict__ efrag,
                                                   const float* __restrict__ en2,
                                                   unsigned long long* __restrict__ packed) {
    __shared__ short sbuf[3][12288];      // 3 x 24 KB
    const int tid = threadIdx.x;
    const int w = tid >> 6, l = tid & 63;
    const int wr = w >> 1, wc = w & 1;
    const int l31 = l & 31, lh = l >> 5;

    int bid = blockIdx.x;                 // 1024 blocks
    int xcd = bid & 7, j = bid >> 3;      // j 0..127
    int row0 = (xcd * 32 + (j >> 2)) * 128;
    int c0   = (j & 3) * 256;

    // A source: wave w converts group g=w; frag lane l = row l31, k lh*8..+7
    const float* axsrc = x + (size_t)(row0 + w * 32 + l31) * DIM + lh * 8;
    // B sources: wave w stages slots 8+w*4+s, s=0..3 -> gb=w*2+(s>>1), h=s&1
    const short* gsrc[4];
    #pragma unroll
    for (int s = 0; s < 4; ++s) {
        int gb = w * 2 + (s >> 1), h = s & 1;
        gsrc[s] = efrag + (size_t)(c0 / 32 + gb) * 32768 + h * 512 + l * 8;
    }

    f32x16 acc[2][4];
    #pragma unroll
    for (int a = 0; a < 2; ++a)
        #pragma unroll
        for (int b = 0; b < 4; ++b)
            #pragma unroll
            for (int r = 0; r < 16; ++r) acc[a][b][r] = 0.f;

    // prologue: A0, B0, A1, B1 (issue order matters for vmcnt counting)
    float4 a00 = *reinterpret_cast<const float4*>(axsrc);
    float4 a01 = *reinterpret_cast<const float4*>(axsrc + 4);
    __builtin_amdgcn_sched_barrier(0);
    #pragma unroll
    for (int s = 0; s < 4; ++s)
        __builtin_amdgcn_global_load_lds((const AS1 void*)gsrc[s],
                                         (AS3 void*)&sbuf[0][(8 + w * 4 + s) * 512],
                                         16, 0, 0);
    __builtin_amdgcn_sched_barrier(0);
    float4 a10 = *reinterpret_cast<const float4*>(axsrc + 16);
    float4 a11 = *reinterpret_cast<const float4*>(axsrc + 20);
    __builtin_amdgcn_sched_barrier(0);
    #pragma unroll
    for (int s = 0; s < 4; ++s)
        __builtin_amdgcn_global_load_lds((const AS1 void*)(gsrc[s] + 1024),
                                         (AS3 void*)&sbuf[1][(8 + w * 4 + s) * 512],
                                         16, 0, 0);
    {
        asm volatile("s_waitcnt vmcnt(10)" ::: "memory");   // A0 done
        short8v hi, lo; conv8(a00, a01, hi, lo);
        *reinterpret_cast<short8v*>(&sbuf[0][(w * 2 + 0) * 512 + l * 8]) = hi;
        *reinterpret_cast<short8v*>(&sbuf[0][(w * 2 + 1) * 512 + l * 8]) = lo;
        asm volatile("s_waitcnt vmcnt(4)" ::: "memory");    // A1 + B0 done
        conv8(a10, a11, hi, lo);
        *reinterpret_cast<short8v*>(&sbuf[1][(w * 2 + 0) * 512 + l * 8]) = hi;
        *reinterpret_cast<short8v*>(&sbuf[1][(w * 2 + 1) * 512 + l * 8]) = lo;
        asm volatile("s_waitcnt lgkmcnt(0)" ::: "memory");
        __builtin_amdgcn_s_barrier();
    }

    #pragma unroll 3
    for (int kb = 0; kb < 30; ++kb) {
        const int cur = kb % 3, nxt = (kb + 2) % 3;
        // issue A(kb+2) fp32 loads, then B(kb+2) DMAs
        float4 an0 = *reinterpret_cast<const float4*>(axsrc + (kb + 2) * 16);
        float4 an1 = *reinterpret_cast<const float4*>(axsrc + (kb + 2) * 16 + 4);
        __builtin_amdgcn_sched_barrier(0);
        #pragma unroll
        for (int s = 0; s < 4; ++s)
            __builtin_amdgcn_global_load_lds(
                (const AS1 void*)(gsrc[s] + (size_t)(kb + 2) * 1024),
                (AS3 void*)&sbuf[nxt][(8 + w * 4 + s) * 512], 16, 0, 0);
        // compute kb
        {
            short8v ah[2], al[2], bh[4], bl[4];
            const short* sb = sbuf[cur];
            #pragma unroll
            for (int m = 0; m < 2; ++m) {
                int g = wr * 2 + m;
                ah[m] = *reinterpret_cast<const short8v*>(&sb[(g * 2 + 0) * 512 + l * 8]);
                al[m] = *reinterpret_cast<const short8v*>(&sb[(g * 2 + 1) * 512 + l * 8]);
            }
            #pragma unroll
            for (int n = 0; n < 4; ++n) {
                int g = 4 + wc * 4 + n;
                bh[n] = *reinterpret_cast<const short8v*>(&sb[(g * 2 + 0) * 512 + l * 8]);
                bl[n] = *reinterpret_cast<const short8v*>(&sb[(g * 2 + 1) * 512 + l * 8]);
            }
            #pragma unroll
            for (int m = 0; m < 2; ++m)
                #pragma unroll
                for (int n = 0; n < 4; ++n) {
                    acc[m][n] = __builtin_amdgcn_mfma_f32_32x32x16_bf16(
                        ah[m], bh[n], acc[m][n], 0, 0, 0);
                    acc[m][n] = __builtin_amdgcn_mfma_f32_32x32x16_bf16(
                        ah[m], bl[n], acc[m][n], 0, 0, 0);
                    acc[m][n] = __builtin_amdgcn_mfma_f32_32x32x16_bf16(
                        al[m], bh[n], acc[m][n], 0, 0, 0);
                }
        }
        // A(kb+2) arrived + B(kb+1) complete; B(kb+2)'s 4 stay in flight
        asm volatile("s_waitcnt vmcnt(4)" ::: "memory");
        {
            short8v hi, lo; conv8(an0, an1, hi, lo);
            *reinterpret_cast<short8v*>(&sbuf[nxt][(w * 2 + 0) * 512 + l * 8]) = hi;
            *reinterpret_cast<short8v*>(&sbuf[nxt][(w * 2 + 1) * 512 + l * 8]) = lo;
        }
        asm volatile("s_waitcnt lgkmcnt(0)" ::: "memory");
        __builtin_amdgcn_s_barrier();
    }

    // epilogue kbs 30, 31 (no further prefetch)
    #pragma unroll
    for (int e = 0; e < 2; ++e) {
        const int kb = 30 + e, cur = kb % 3;
        short8v ah[2], al[2], bh[4], bl[4];
        const short* sb = sbuf[cur];
        #pragma unroll
        for (int m = 0; m < 2; ++m) {
            int g = wr * 2 + m;
            ah[m] = *reinterpret_cast<const short8v*>(&sb[(g * 2 + 0) * 512 + l * 8]);
            al[m] = *reinterpret_cast<const short8v*>(&sb[(g * 2 + 1) * 512 + l * 8]);
        }
        #pragma unroll
        for (int n = 0; n < 4; ++n) {
            int g = 4 + wc * 4 + n;
            bh[n] = *reinterpret_cast<const short8v*>(&sb[(g * 2 + 0) * 512 + l * 8]);
            bl[n] = *reinterpret_cast<const short8v*>(&sb[(g * 2 + 1) * 512 + l * 8]);
        }
        #pragma unroll
        for (int m = 0; m < 2; ++m)
            #pragma unroll
            for (int n = 0; n < 4; ++n) {
                acc[m][n] = __builtin_amdgcn_mfma_f32_32x32x16_bf16(
                    ah[m], bh[n], acc[m][n], 0, 0, 0);
                acc[m][n] = __builtin_amdgcn_mfma_f32_32x32x16_bf16(
                    ah[m], bl[n], acc[m][n], 0, 0, 0);
                acc[m][n] = __builtin_amdgcn_mfma_f32_32x32x16_bf16(
                    al[m], bh[n], acc[m][n], 0, 0, 0);
            }
        if (e == 0) {
            asm volatile("s_waitcnt vmcnt(0) lgkmcnt(0)" ::: "memory");
            __builtin_amdgcn_s_barrier();
        }
    }

    // epilogue: dist = ||e||^2 - 2 x.e ; D layout: col=l&31,
    // row=(r&3)+8*(r>>2)+4*(l>>5)
    float e2[4];
    #pragma unroll
    for (int n = 0; n < 4; ++n) e2[n] = en2[c0 + wc * 128 + n * 32 + l31];
    #pragma unroll
    for (int m = 0; m < 2; ++m) {
        #pragma unroll
        for (int r = 0; r < 16; ++r) {
            unsigned long long key = 0xFFFFFFFFFFFFFFFFull;
            #pragma unroll
            for (int n = 0; n < 4; ++n) {
                float d = fmaf(-2.f, acc[m][n][r], e2[n]);
                unsigned long long k = pack_key(d, c0 + wc * 128 + n * 32 + l31);
                if (k < key) key = k;
            }
            #pragma unroll
            for (int off = 1; off < 32; off <<= 1) {
                unsigned long long o = __shfl_xor(key, off);
                if (o < key) key = o;
            }
            if (l31 == 0) {
                int grow = row0 + wr * 64 + m * 32 + (r & 3) + 8 * (r >> 2) + 4 * lh;
                atomicMin(&packed[grow], key);
            }
        }
    }
}

// ---------------- unpack idx + histogram ----------------
__global__ __launch_bounds__(256) void k_hist(const unsigned long long* __restrict__ packed,
                                              int* __restrict__ idx,
                                              int* __restrict__ counts) {
    __shared__ int h[KC];
    for (int i = threadIdx.x; i < KC; i += 256) h[i] = 0;
    __syncthreads();
    int g = blockIdx.x * 256 + threadIdx.x;
    int c = (int)(unsigned)(packed[g] & 0xFFFFFFFFull);
    idx[g] = c;
    atomicAdd(&h[c], 1);
    __syncthreads();
    for (int i = threadIdx.x; i < KC; i += 256)
        if (h[i]) atomicAdd(&counts[i], h[i]);
}

// ---------------- smoothing, perplexity, prefix sums (1-barrier) ----------
__global__ __launch_bounds__(1024) void k_meta(const int* __restrict__ counts,
                                               const float* __restrict__ ema_cs,
                                               float* __restrict__ smoothed,
                                               int* __restrict__ offsets,
                                               int* __restrict__ cursor,
                                               float* __restrict__ perp_out) {
    __shared__ float ws1[16], ws2[16];
    __shared__ int wsum[16];
    int t = threadIdx.x, lane = t & 63, w = t >> 6;
    int cnt = counts[t];
    float cs = ema_cs[t] * 0.99f + 0.01f * (float)cnt;
    float p = (float)cnt / 32768.f;
    float v1 = cs, v2 = p * logf(p + 1e-10f);
    #pragma unroll
    for (int off = 32; off; off >>= 1) {
        v1 += __shfl_xor(v1, off);
        v2 += __shfl_xor(v2, off);
    }
    int s = cnt;
    #pragma unroll
    for (int off = 1; off < 64; off <<= 1) {
        int u = __shfl_up(s, off);
        if (lane >= off) s += u;
    }
    if (lane == 0) { ws1[w] = v1; ws2[w] = v2; }
    if (lane == 63) wsum[w] = s;
    __syncthreads();
    float n = 0.f;
    #pragma unroll
    for (int i = 0; i < 16; ++i) n += ws1[i];
    smoothed[t] = (cs + 1e-5f) / (n + 1024.f * 1e-5f) * n;
    if (t == 0) {
        float sp = 0.f;
        #pragma unroll
        for (int i = 0; i < 16; ++i) sp += ws2[i];
        perp_out[0] = expf(-sp);
    }
    int wo = 0;
    for (int i = 0; i < 16; ++i) if (i < w) wo += wsum[i];
    int off_ = wo + s - cnt;   // exclusive prefix (exact int)
    offsets[t] = off_;
    cursor[t] = off_;
}

// ---------------- CSR bucket scatter ----------------
__global__ __launch_bounds__(256) void k_scatter(const int* __restrict__ idx,
                                                 int* __restrict__ cursor,
                                                 int* __restrict__ bucket) {
    int g = blockIdx.x * 256 + threadIdx.x;
    int c = idx[g];
    int pos = atomicAdd(&cursor[c], 1);
    bucket[pos] = g;
}

// ---------------- segment-sum + new embedding (2 half-dim blocks/code) ----
__global__ __launch_bounds__(256) void k_dw(const float* __restrict__ x,
                                            const float* __restrict__ ema_w,
                                            const int* __restrict__ offsets,
                                            const int* __restrict__ counts,
                                            const int* __restrict__ bucket,
                                            const float* __restrict__ smoothed,
                                            float* __restrict__ newE) {
    __shared__ int rows[256];
    int k = blockIdx.x >> 1, half = blockIdx.x & 1, t = threadIdx.x;
    int d = half * 256 + t;
    int beg = offsets[k], m = counts[k];
    float a = 0.f;
    for (int base = 0; base < m; base += 256) {
        int n = min(256, m - base);
        __syncthreads();
        if (t < n) rows[t] = bucket[beg + base + t];
        __syncthreads();
        int i = 0;
        for (; i + 4 <= n; i += 4) {
            float v0 = x[(size_t)rows[i]     * DIM + d];
            float v1 = x[(size_t)rows[i + 1] * DIM + d];
            float v2 = x[(size_t)rows[i + 2] * DIM + d];
            float v3 = x[(size_t)rows[i + 3] * DIM + d];
            a += v0 + v1 + v2 + v3;
        }
        for (; i < n; ++i) a += x[(size_t)rows[i] * DIM + d];
    }
    newE[(size_t)k * DIM + d] =
        (ema_w[(size_t)k * DIM + d] * 0.99f + 0.01f * a) / smoothed[k];
}

// ---------------- fused quantized (STE) + one-hot + loss partials ---------
__global__ __launch_bounds__(256) void k_qe(const float* __restrict__ x,
                                            const int* __restrict__ idx,
                                            const float* __restrict__ newE,
                                            float* __restrict__ outq,
                                            float* __restrict__ enc,
                                            float* __restrict__ partials) {
    int b = blockIdx.x, t = threadIdx.x;
    int row8 = b * 8;
    float lp = 0.f;
    #pragma unroll
    for (int it = 0; it < 4; ++it) {
        int slot = t + it * 256;
        int r = slot >> 7;
        int c4 = (slot & 127) * 4;
        int row = row8 + r;
        int code = idx[row];
        float4 in = *reinterpret_cast<const float4*>(&x[(size_t)row * DIM + c4]);
        float4 q  = *reinterpret_cast<const float4*>(&newE[(size_t)code * DIM + c4]);
        float4 d;
        d.x = q.x - in.x; d.y = q.y - in.y; d.z = q.z - in.z; d.w = q.w - in.w;
        float4 o;
        o.x = in.x + d.x; o.y = in.y + d.y; o.z = in.z + d.z; o.w = in.w + d.w;
        *reinterpret_cast<float4*>(&outq[(size_t)row * DIM + c4]) = o;
        lp += d.x*d.x + d.y*d.y + d.z*d.z + d.w*d.w;
    }
    {
        int er = row8 + (t >> 5);
        int l32 = t & 31;
        int one = idx[er];
        float4* dst = reinterpret_cast<float4*>(enc + (size_t)er * KC);
        #pragma unroll
        for (int s = 0; s < 8; ++s) {
            int c4 = l32 + s * 32;
            int base = c4 * 4;
            float4 v;
            v.x = (one == base)     ? 1.f : 0.f;
            v.y = (one == base + 1) ? 1.f : 0.f;
            v.z = (one == base + 2) ? 1.f : 0.f;
            v.w = (one == base + 3) ? 1.f : 0.f;
            dst[c4] = v;
        }
    }
    #pragma unroll
    for (int off = 32; off; off >>= 1) lp += __shfl_xor(lp, off);
    __shared__ float wr[4];
    int lane = t & 63, w = t >> 6;
    if (!lane) wr[w] = lp;
    __syncthreads();
    if (t == 0) partials[b] = wr[0] + wr[1] + wr[2] + wr[3];
}

__global__ __launch_bounds__(256) void k_lossfin(const float* __restrict__ partials,
                                                 float* __restrict__ out0) {
    __shared__ double red[256];
    double s = 0.0;
    for (int i = threadIdx.x; i < 4096; i += 256) s += (double)partials[i];
    red[threadIdx.x] = s; __syncthreads();
    for (int st = 128; st; st >>= 1) {
        if (threadIdx.x < st) red[threadIdx.x] += red[threadIdx.x + st];
        __syncthreads();
    }
    if (!threadIdx.x) out0[0] = (float)(0.25 * red[0] / 16777216.0);
}

extern "C" void kernel_launch(void* const* d_in, const int* in_sizes, int n_in,
                              void* d_out, int out_size, void* d_ws, size_t ws_size,
                              hipStream_t stream) {
    const float* x   = (const float*)d_in[0];
    const float* E   = (const float*)d_in[1];
    const float* ecs = (const float*)d_in[2];
    const float* emw = (const float*)d_in[3];
    float* out = (float*)d_out;

    char* ws = (char*)d_ws;
    int*   idx      = (int*)(ws + 0);                  // 128 KB
    int*   bucket   = (int*)(ws + 131072);             // 128 KB
    float* en2      = (float*)(ws + 262144);           // 4 KB
    int*   counts   = (int*)(ws + 266240);             // 4 KB
    int*   offsets  = (int*)(ws + 270336);             // 4 KB
    int*   cursor   = (int*)(ws + 274432);             // 4 KB
    float* smoothed = (float*)(ws + 278528);           // 4 KB
    float* newE     = (float*)(ws + 282624);           // 2 MB
    float* partials = (float*)(ws + 282624 + 2097152); // 16 KB
    unsigned long long* packed = (unsigned long long*)newE;  // dead before k_dw

    float* out_loss = out;
    float* out_q    = out + 1;
    float* out_perp = out + 16777217;
    float* out_enc  = out + 16777218;

    // efrag scratch lives in out_enc (2 MB of 128 MB, rewritten by k_qe later)
    short* efrag = (short*)out_enc;

    k_eprep  <<<KC / 32, 256, 0, stream>>>(E, efrag, en2, counts, packed);
    k_argmin <<<(NROWS / 128) * 4, 256, 0, stream>>>(x, efrag, en2, packed);
    k_hist   <<<NROWS / 256, 256, 0, stream>>>(packed, idx, counts);
    k_meta   <<<1, 1024, 0, stream>>>(counts, ecs, smoothed, offsets, cursor, out_perp);
    k_scatter<<<NROWS / 256, 256, 0, stream>>>(idx, cursor, bucket);
    k_dw     <<<KC * 2, 256, 0, stream>>>(x, emw, offsets, counts, bucket, smoothed, newE);
    k_qe     <<<NROWS / 8, 256, 0, stream>>>(x, idx, newE, out_q, out_enc, partials);
    k_lossfin<<<1, 256, 0, stream>>>(partials, out_loss);
}